// Round 5
// baseline (4875.614 us; speedup 1.0000x reference)
//
#include <hip/hip_runtime.h>
#include <hip/hip_bf16.h>

#define B_   64
#define S_   800
#define DIN_ 64
#define D_   512
#define H_   8
#define DH_  64
#define M_   64
#define L_   2
#define FF_  2048

typedef __hip_bfloat16 bf16;
typedef __attribute__((ext_vector_type(8))) short bf16x8;
typedef __attribute__((ext_vector_type(4))) float f32x4;

#define NORM_ 0.35355339059327373f   // 64^(-1/4)

__device__ __forceinline__ unsigned flipf(float f){
  unsigned u = __float_as_uint(f);
  return u ^ (((unsigned)((int)u >> 31)) | 0x80000000u);
}
__device__ __forceinline__ float unflipf(unsigned u){
  unsigned b = (u & 0x80000000u) ? (u ^ 0x80000000u) : ~u;
  return __uint_as_float(b);
}
__device__ __forceinline__ float gelu_f(float x){
  float x3 = x*x*x;
  return 0.5f*x*(1.f + tanhf(0.7978845608028654f*(x + 0.044715f*x3)));
}
__device__ __forceinline__ void st_bf4(bf16* p, float4 v){
  union { bf16 b[4]; unsigned long long u; } q;
  q.b[0]=__float2bfloat16(v.x); q.b[1]=__float2bfloat16(v.y);
  q.b[2]=__float2bfloat16(v.z); q.b[3]=__float2bfloat16(v.w);
  *(unsigned long long*)p = q.u;
}
__device__ __forceinline__ void gld16(const void* g, void* l){
  __builtin_amdgcn_global_load_lds((const __attribute__((address_space(1))) void*)g,
                                   (__attribute__((address_space(3))) void*)l, 16, 0, 0);
}

// ---------------- shared MFMA tile core (m97 + T2 chunk-XOR swizzle) -------
// A bf16 [rows][K], Wt bf16 [N][K]. 128x128 tile, BK=32, 256 thr = 4 waves.
// LDS [128 rows][4 chunks of 16B]; chunk position p of row r holds global
// chunk p ^ ((r>>1)&3)  (write side: pre-swizzled global source, linear LDS
// dest; read side: same XOR) -> each 16-lane quarter hits 2 lanes/bank-group.
__device__ __forceinline__ void gemm_tile(const bf16* __restrict__ A,
                                          const bf16* __restrict__ Wt,
                                          int rows, int K, f32x4 (&acc)[4][4])
{
  __shared__ bf16 As[128*32];
  __shared__ bf16 Bs[128*32];
  const int tid = threadIdx.x, wave = tid>>6, lane = tid&63;
  const int row0 = blockIdx.y*128, col0 = blockIdx.x*128;
  const int wm = (wave>>1)*64, wn = (wave&1)*64;
  const int lr = lane&15;
  const int lk = ((lane>>4) ^ ((lane>>1)&3))*8;       // swizzled read offset
  const int c0 = wave*2, c1 = c0+1;
  const int sub = lane>>2;
  const int kq = (((lane&3) ^ ((lane>>3)&3)))*8;      // swizzled source chunk
  const int ra0 = min(row0 + c0*16 + sub, rows-1);
  const int ra1 = min(row0 + c1*16 + sub, rows-1);
  const bf16* gA0 = A + (size_t)ra0*K + kq;
  const bf16* gA1 = A + (size_t)ra1*K + kq;
  const bf16* gB0 = Wt + (size_t)(col0 + c0*16 + sub)*K + kq;
  const bf16* gB1 = Wt + (size_t)(col0 + c1*16 + sub)*K + kq;
  bf16* lA0 = &As[c0*512]; bf16* lA1 = &As[c1*512];
  bf16* lB0 = &Bs[c0*512]; bf16* lB1 = &Bs[c1*512];
  for (int k0=0; k0<K; k0+=32){
    __syncthreads();                       // prev tile fully consumed
    gld16(gA0 + k0, lA0);  gld16(gA1 + k0, lA1);
    gld16(gB0 + k0, lB0);  gld16(gB1 + k0, lB1);
    __syncthreads();                       // drains vmcnt -> LDS valid
    bf16x8 af[4], bv[4];
    #pragma unroll
    for (int mi=0;mi<4;mi++) af[mi] = *(const bf16x8*)&As[(wm+mi*16+lr)*32 + lk];
    #pragma unroll
    for (int ni=0;ni<4;ni++) bv[ni] = *(const bf16x8*)&Bs[(wn+ni*16+lr)*32 + lk];
    #pragma unroll
    for (int mi=0;mi<4;mi++)
      #pragma unroll
      for (int ni=0;ni<4;ni++)
        acc[mi][ni] = __builtin_amdgcn_mfma_f32_16x16x32_bf16(af[mi], bv[ni], acc[mi][ni], 0,0,0);
  }
}

// ---------------- standard GEMM: C = act(A@W + bias) (+res) ----------------
template<int ACT, int RES, int OUTB>
__global__ __launch_bounds__(256)
void gemm2_k(const bf16* __restrict__ A, const bf16* __restrict__ Wt,
             const float* __restrict__ bias, const float* __restrict__ res,
             float* __restrict__ Cf, bf16* __restrict__ Cb,
             int rows, int N, int K, int res_mod)
{
  f32x4 acc[4][4];
  #pragma unroll
  for (int i=0;i<4;i++)
    #pragma unroll
    for (int j=0;j<4;j++) acc[i][j] = (f32x4){0.f,0.f,0.f,0.f};
  gemm_tile(A, Wt, rows, K, acc);
  const int tid=threadIdx.x, wave=tid>>6, lane=tid&63;
  const int wm=(wave>>1)*64, wn=(wave&1)*64, lr=lane&15, hi=lane>>4;
  const int row0=blockIdx.y*128, col0=blockIdx.x*128;
  #pragma unroll
  for (int mi=0;mi<4;mi++){
    #pragma unroll
    for (int i=0;i<4;i++){
      const int r = row0 + wm + mi*16 + hi*4 + i;
      if (r >= rows) continue;
      #pragma unroll
      for (int ni=0;ni<4;ni++){
        const int c = col0 + wn + ni*16 + lr;
        float v = acc[mi][ni][i] + bias[c];
        if (ACT) v = gelu_f(v);
        if (RES) v += res[(size_t)(res_mod ? (r % res_mod) : r)*N + c];
        if (OUTB) Cb[(size_t)r*N + c] = __float2bfloat16(v);
        else      Cf[(size_t)r*N + c] = v;
      }
    }
  }
}

// ---------------- mega GEMM: N=2560, per-head interleaved ------------------
// cols: [0,1024)   = 8 pairs [q_h(64)|ddq_h(64)]
//       [1024,2048)= 8 pairs [k_h(64)|ddk_h(64)]
//       [2048,2560)= v
// q/k-waves (wn==0) -> diag into LDS;  dd-waves (wn==64): store dd-diag,
// q: per-row max -> dqmax[r][h];  k: global per-(b,h) max -> atomicMax.
// v-blocks store bf16.
__global__ __launch_bounds__(256)
void gemm_mega_k(const bf16* __restrict__ A, const bf16* __restrict__ Wcat,
                 const float* __restrict__ bcat, int rows,
                 float* __restrict__ ddq, float* __restrict__ ddk,
                 bf16* __restrict__ vbf, float* __restrict__ dqmax,
                 unsigned* __restrict__ kmaxU)
{
  __shared__ float diagL[128];
  f32x4 acc[4][4];
  #pragma unroll
  for (int i=0;i<4;i++)
    #pragma unroll
    for (int j=0;j<4;j++) acc[i][j] = (f32x4){0.f,0.f,0.f,0.f};
  gemm_tile(A, Wcat, rows, 512, acc);
  const int tid=threadIdx.x, wave=tid>>6, lane=tid&63;
  const int wm=(wave>>1)*64, wn=(wave&1)*64, lr=lane&15, hi=lane>>4;
  const int row0 = blockIdx.y*128;
  const int x = blockIdx.x;
  if (x < 16){
    const int isK = x>>3, h = x&7;
    const int cbase = x*128 + wn;
    if (wn == 0){   // q/k wave: diag = 0.5*NORM^2 * sum(val^2)
      #pragma unroll
      for (int mi=0;mi<4;mi++){
        #pragma unroll
        for (int i=0;i<4;i++){
          float s = 0.f;
          #pragma unroll
          for (int ni=0;ni<4;ni++){
            float v = acc[mi][ni][i] + bcat[cbase + ni*16 + lr];
            s += v*v;
          }
          s += __shfl_xor(s,1); s += __shfl_xor(s,2);
          s += __shfl_xor(s,4); s += __shfl_xor(s,8);
          if (lr==0) diagL[wm + mi*16 + hi*4 + i] = 0.0625f*s;  // 0.5*(1/8)
        }
      }
    }
    __syncthreads();
    if (wn == 64){  // dd wave
      float* dst = isK ? ddk : ddq;
      #pragma unroll
      for (int mi=0;mi<4;mi++){
        #pragma unroll
        for (int i=0;i<4;i++){
          const int r = row0 + wm + mi*16 + hi*4 + i;
          float vv[4]; float mx = -3.4e38f;
          #pragma unroll
          for (int ni=0;ni<4;ni++){
            vv[ni] = acc[mi][ni][i] + bcat[cbase + ni*16 + lr];
            mx = fmaxf(mx, vv[ni]);
          }
          mx = fmaxf(mx, __shfl_xor(mx,1)); mx = fmaxf(mx, __shfl_xor(mx,2));
          mx = fmaxf(mx, __shfl_xor(mx,4)); mx = fmaxf(mx, __shfl_xor(mx,8));
          if (r < rows){
            const float dg = diagL[wm + mi*16 + hi*4 + i];
            if (!isK){
              if (lr==0) dqmax[(size_t)r*8 + h] = mx;
            } else {
              if (lr==0) atomicMax(&kmaxU[(r/S_)*8 + h], flipf(mx));
            }
            #pragma unroll
            for (int ni=0;ni<4;ni++)
              dst[(size_t)r*512 + h*64 + ni*16 + lr] = vv[ni] - dg;
          }
        }
      }
    }
  } else {          // v block
    const int colb = (x-16)*128 + wn;
    #pragma unroll
    for (int mi=0;mi<4;mi++){
      #pragma unroll
      for (int i=0;i<4;i++){
        const int r = row0 + wm + mi*16 + hi*4 + i;
        if (r >= rows) continue;
        #pragma unroll
        for (int ni=0;ni<4;ni++){
          const int c = colb + ni*16 + lr;
          vbf[(size_t)r*512 + c] = __float2bfloat16(acc[mi][ni][i] + bcat[2048 + c]);
        }
      }
    }
  }
}

// ------- weight transpose+convert with column remap ------------------------
// src f32 [K][N] -> dst rows: row(n) = mapbase + (n>>6)*mapstride + (n&63)
__global__ __launch_bounds__(256)
void convT_k(const float* __restrict__ src, bf16* __restrict__ dst, int K, int N,
             int mapbase, int mapstride)
{
  __shared__ float t[32][33];
  const int n0 = blockIdx.x*32, k0 = blockIdx.y*32;
  const int j = threadIdx.x&31, i0 = threadIdx.x>>5;
  #pragma unroll
  for (int i=i0; i<32; i+=8) t[i][j] = src[(size_t)(k0+i)*N + n0 + j];
  __syncthreads();
  #pragma unroll
  for (int i=i0; i<32; i+=8){
    const int n = n0 + i;
    const int rn = mapbase + (n>>6)*mapstride + (n&63);
    dst[(size_t)rn*K + k0 + j] = __float2bfloat16(t[j][i]);
  }
}

__global__ void conv_k(const float* __restrict__ src, bf16* __restrict__ dst, int n4)
{
  int i = blockIdx.x*256 + threadIdx.x;
  if (i < n4){ float4 v = ((const float4*)src)[i]; st_bf4(dst + (size_t)i*4, v); }
}

// folded feature weight into Wcat: out row = mapbase + h*128 + m
__global__ __launch_bounds__(256)
void projw_k(const float* __restrict__ w, const float* __restrict__ proj,
             bf16* __restrict__ Wcat, int mapbase)
{
  __shared__ float pj[64][64];
  __shared__ float wsh[64][65];
  const int h = blockIdx.x, c0 = blockIdx.y*64;
  const int tid = threadIdx.x, lane = tid&63, tg = tid>>6;
  for (int i=tid; i<4096; i+=256) pj[i>>6][i&63] = proj[i];
  for (int i=tg; i<64; i+=4) wsh[i][lane] = w[(size_t)(c0+i)*512 + h*64 + lane];
  __syncthreads();
  float acc[16];
  #pragma unroll
  for (int j=0;j<16;j++) acc[j]=0.f;
  for (int d=0; d<64; ++d){
    float wv = wsh[lane][d];
    #pragma unroll
    for (int j=0;j<16;j++) acc[j] += wv * pj[tg*16+j][d];
  }
  #pragma unroll
  for (int j=0;j<16;j++)
    Wcat[(size_t)(mapbase + h*128 + tg*16 + j)*512 + c0 + lane] = __float2bfloat16(acc[j]*NORM_);
}

// bias pack for the interleaved 2560-col layout
__global__ void bpack_k(const float* __restrict__ bq, const float* __restrict__ bk,
                        const float* __restrict__ bv, const float* __restrict__ proj,
                        float* __restrict__ bl)
{
  int idx = blockIdx.x*256 + threadIdx.x;
  if (idx >= 2560) return;
  float v;
  if (idx < 2048){
    const float* bsrc = (idx<1024)? bq : bk;
    int t = idx & 1023;
    int h = t>>7, w = t&127;
    if (w < 64) v = bsrc[h*64+w];
    else {
      int m = w-64; float acc=0.f;
      for (int d=0; d<64; ++d) acc += bsrc[h*64+d]*proj[m*64+d];
      v = acc*NORM_;
    }
  } else v = bv[idx-2048];
  bl[idx] = v;
}

// ---------------- LayerNorm (grid-stride, bf16 out) ------------------------
__global__ __launch_bounds__(256)
void ln_k(const float* __restrict__ x, const float* __restrict__ g,
          const float* __restrict__ b, bf16* __restrict__ y, int nrows)
{
  const int wid = threadIdx.x>>6, lane = threadIdx.x&63;
  float4 g0 = *(const float4*)(g + lane*4);
  float4 g1 = *(const float4*)(g + 256 + lane*4);
  float4 b0 = *(const float4*)(b + lane*4);
  float4 b1 = *(const float4*)(b + 256 + lane*4);
  for (size_t row = (size_t)blockIdx.x*4 + wid; row < (size_t)nrows; row += (size_t)gridDim.x*4){
    const float* xr = x + row*D_;
    float4 v0 = *(const float4*)(xr + lane*4);
    float4 v1 = *(const float4*)(xr + 256 + lane*4);
    float s  = v0.x+v0.y+v0.z+v0.w + v1.x+v1.y+v1.z+v1.w;
    float ss = v0.x*v0.x+v0.y*v0.y+v0.z*v0.z+v0.w*v0.w
             + v1.x*v1.x+v1.y*v1.y+v1.z*v1.z+v1.w*v1.w;
    #pragma unroll
    for (int o=32;o;o>>=1){ s += __shfl_xor(s,o); ss += __shfl_xor(ss,o); }
    const float mean = s*(1.f/D_);
    const float rstd = rsqrtf(ss*(1.f/D_) - mean*mean + 1e-5f);
    float4 o0, o1;
    o0.x=(v0.x-mean)*rstd*g0.x+b0.x; o0.y=(v0.y-mean)*rstd*g0.y+b0.y;
    o0.z=(v0.z-mean)*rstd*g0.z+b0.z; o0.w=(v0.w-mean)*rstd*g0.w+b0.w;
    o1.x=(v1.x-mean)*rstd*g1.x+b1.x; o1.y=(v1.y-mean)*rstd*g1.y+b1.y;
    o1.z=(v1.z-mean)*rstd*g1.z+b1.z; o1.w=(v1.w-mean)*rstd*g1.w+b1.w;
    bf16* yr = y + row*D_;
    st_bf4(yr + lane*4, o0);
    st_bf4(yr + 256 + lane*4, o1);
  }
}

__global__ void kinit_k(unsigned* __restrict__ kmax, int n){
  int i = blockIdx.x*256 + threadIdx.x;
  if (i < n) kmax[i] = 0u;   // flipped-float identity
}

// ------- fused featK + kps + ctx: per-(b,h) block --------------------------
// kp[s][m] = 0.125*(exp(ddk'[s][m] - stab)+eps) computed on the fly;
// ctx[m][d] += kp[s][m]*v[s][d];  kps[m] = sum_s kp[s][m].  kp never stored.
__global__ __launch_bounds__(256)
void fctx_k(const float* __restrict__ ddk, const bf16* __restrict__ vbf,
            const unsigned* __restrict__ kmaxU,
            float* __restrict__ ctx, float* __restrict__ kps)
{
  __shared__ float kc[32][64], vc[32][64];
  const int bh = blockIdx.x, tid = threadIdx.x;
  const int b = bh>>3, h = bh&7;
  const float stab = unflipf(kmaxU[bh]);
  const int mq = tid>>4, dq = tid&15;
  const int cc = (tid&15)*4;
  float acc[4][4];
  #pragma unroll
  for (int i=0;i<4;i++)
    #pragma unroll
    for (int j=0;j<4;j++) acc[i][j]=0.f;
  float kpart[4] = {0.f,0.f,0.f,0.f};
  for (int s0=0; s0<S_; s0+=32){
    #pragma unroll
    for (int ii=0; ii<2; ++ii){
      const int rr = (tid>>4) + ii*16;
      const size_t grow = (size_t)(b*S_+s0+rr)*512 + h*64 + cc;
      float4 d4 = *(const float4*)(ddk + grow);
      float4 kv;
      kv.x = 0.125f*(expf(d4.x - stab)+1e-4f);
      kv.y = 0.125f*(expf(d4.y - stab)+1e-4f);
      kv.z = 0.125f*(expf(d4.z - stab)+1e-4f);
      kv.w = 0.125f*(expf(d4.w - stab)+1e-4f);
      *(float4*)&kc[rr][cc] = kv;
      kpart[0]+=kv.x; kpart[1]+=kv.y; kpart[2]+=kv.z; kpart[3]+=kv.w;
      const bf16* vp = vbf + grow;
      float4 vv;
      vv.x = __bfloat162float(vp[0]); vv.y = __bfloat162float(vp[1]);
      vv.z = __bfloat162float(vp[2]); vv.w = __bfloat162float(vp[3]);
      *(float4*)&vc[rr][cc] = vv;
    }
    __syncthreads();
    #pragma unroll 8
    for (int ssi=0; ssi<32; ++ssi){
      float a0=kc[ssi][mq*4+0],a1=kc[ssi][mq*4+1],a2=kc[ssi][mq*4+2],a3=kc[ssi][mq*4+3];
      float b0=vc[ssi][dq*4+0],b1=vc[ssi][dq*4+1],b2=vc[ssi][dq*4+2],b3=vc[ssi][dq*4+3];
      acc[0][0]+=a0*b0; acc[0][1]+=a0*b1; acc[0][2]+=a0*b2; acc[0][3]+=a0*b3;
      acc[1][0]+=a1*b0; acc[1][1]+=a1*b1; acc[1][2]+=a1*b2; acc[1][3]+=a1*b3;
      acc[2][0]+=a2*b0; acc[2][1]+=a2*b1; acc[2][2]+=a2*b2; acc[2][3]+=a2*b3;
      acc[3][0]+=a3*b0; acc[3][1]+=a3*b1; acc[3][2]+=a3*b2; acc[3][3]+=a3*b3;
    }
    __syncthreads();
  }
  #pragma unroll
  for (int i=0;i<4;i++)
    #pragma unroll
    for (int j=0;j<4;j++)
      ctx[((size_t)bh*64 + mq*4+i)*64 + dq*4+j] = acc[i][j];
  // kps reduce: thread t held cols (t&15)*4+j
  float* kcf = &kc[0][0];
  #pragma unroll
  for (int j=0;j<4;j++) kcf[tid*4+j] = kpart[j];
  __syncthreads();
  if (tid < 64){
    const int m = tid;
    float s = 0.f;
    #pragma unroll
    for (int g=0; g<16; ++g) s += kcf[(g*16 + (m>>2))*4 + (m&3)];
    kps[bh*64 + m] = s;
  }
}

// ------- attn out: qp computed in-reg from ddq' + dqmax --------------------
__global__ __launch_bounds__(256)
void attnout_k(const float* __restrict__ ddq, const float* __restrict__ dqmax,
               const float* __restrict__ ctx, const float* __restrict__ kps,
               bf16* __restrict__ out)
{
  __shared__ float cl[4096];
  __shared__ float kl[64];
  __shared__ float qL[4][64];
  const int bh = blockIdx.x, tid = threadIdx.x;
  for (int i=tid;i<4096;i+=256) cl[i] = ctx[(size_t)bh*4096 + i];
  if (tid<64) kl[tid] = kps[bh*64+tid];
  const int b = bh>>3, h = bh&7;
  const int d = tid&63, sg = tid>>6;
  const int send = min((int)(blockIdx.y*64+64), S_);
  for (int s0 = blockIdx.y*64; s0 < send; s0 += 4){
    const int sr = s0 + sg;
    const size_t rrow = (size_t)(b*S_+sr);
    float dv = ddq[rrow*512 + h*64 + d];
    float mx = dqmax[rrow*8 + h];
    float qp = 0.125f*(expf(dv - mx)+1e-4f);
    __syncthreads();
    qL[sg][d] = qp;
    __syncthreads();
    float a0=0,a1=0,a2=0,a3=0, e0=0,e1=0,e2=0,e3=0;
    #pragma unroll
    for (int m=0;m<64;m+=4){
      float q0=qL[sg][m], q1=qL[sg][m+1], q2=qL[sg][m+2], q3=qL[sg][m+3];
      a0 += q0*cl[(m  )*64+d]; a1 += q1*cl[(m+1)*64+d];
      a2 += q2*cl[(m+2)*64+d]; a3 += q3*cl[(m+3)*64+d];
      e0 += q0*kl[m]; e1 += q1*kl[m+1]; e2 += q2*kl[m+2]; e3 += q3*kl[m+3];
    }
    const float den = (e0+e1)+(e2+e3);
    const float o = ((a0+a1)+(a2+a3))/den;
    out[(rrow*H_ + h)*64 + d] = __float2bfloat16(o);
  }
}

// ---------------- head ----------------------------------------------------
__global__ __launch_bounds__(256)
void head_k(const float* __restrict__ h, const float* __restrict__ fcw,
            const float* __restrict__ fcb, float* __restrict__ out)
{
  __shared__ float red[256][2];
  const int b = blockIdx.x, tid = threadIdx.x;
  const float* hb = h + (size_t)b*S_*D_;
  float s0=0.f, s1=0.f;
  for (int s=0; s<S_; ++s){
    s0 += hb[(size_t)s*D_ + tid];
    s1 += hb[(size_t)s*D_ + tid + 256];
  }
  const float m0 = s0*(1.f/S_), m1 = s1*(1.f/S_);
  red[tid][0] = m0*fcw[tid*2+0] + m1*fcw[(tid+256)*2+0];
  red[tid][1] = m0*fcw[tid*2+1] + m1*fcw[(tid+256)*2+1];
  __syncthreads();
  for (int st=128; st; st>>=1){
    if (tid<st){ red[tid][0]+=red[tid+st][0]; red[tid][1]+=red[tid+st][1]; }
    __syncthreads();
  }
  if (tid==0){ out[b*2+0]=red[0][0]+fcb[0]; out[b*2+1]=red[0][1]+fcb[1]; }
}

extern "C" void kernel_launch(void* const* d_in, const int* in_sizes, int n_in,
                              void* d_out, int out_size, void* d_ws, size_t ws_size,
                              hipStream_t stream)
{
  const float* x     = (const float*)d_in[0];
  const float* emb_w = (const float*)d_in[1];
  const float* emb_b = (const float*)d_in[2];
  const float* pos   = (const float*)d_in[3];
  const float* ln1_g = (const float*)d_in[4];
  const float* ln1_b = (const float*)d_in[5];
  const float* wq    = (const float*)d_in[6];
  const float* bq    = (const float*)d_in[7];
  const float* wk    = (const float*)d_in[8];
  const float* bk    = (const float*)d_in[9];
  const float* wv    = (const float*)d_in[10];
  const float* bv    = (const float*)d_in[11];
  const float* wo    = (const float*)d_in[12];
  const float* bo    = (const float*)d_in[13];
  const float* proj  = (const float*)d_in[14];
  const float* ln2_g = (const float*)d_in[15];
  const float* ln2_b = (const float*)d_in[16];
  const float* w1    = (const float*)d_in[17];
  const float* b1    = (const float*)d_in[18];
  const float* w2    = (const float*)d_in[19];
  const float* b2    = (const float*)d_in[20];
  const float* fc_w  = (const float*)d_in[21];
  const float* fc_b  = (const float*)d_in[22];
  float* out = (float*)d_out;

  const size_t W55 = (size_t)512*512, W52 = (size_t)512*2048;
  const size_t WCAT = (size_t)2560*512;

  char* p = (char*)d_ws;
  auto take = [&](size_t bytes)->char*{
    char* r = p; p += (bytes + 255) & ~(size_t)255; return r;
  };
  bf16* Wcat = (bf16*)take(L_*WCAT*2);
  bf16* woT  = (bf16*)take(L_*W55*2);
  bf16* w1T  = (bf16*)take(L_*W52*2);
  bf16* w2T  = (bf16*)take(L_*W52*2);
  bf16* embT = (bf16*)take((size_t)64*512*2);
  bf16* xbf  = (bf16*)take((size_t)B_*S_*DIN_*2);
  float* bcat= (float*)take(L_*2560*4);
  const size_t fixed_bytes = (size_t)(p - (char*)d_ws);

  int NB = 64; size_t need = 0;
  for (;; NB >>= 1){
    size_t RC = (size_t)NB*S_, nbh = (size_t)NB*H_;
    need = fixed_bytes + RC*8192 + RC*32 + nbh*(16384+256+4) + 65536;
    if (need <= ws_size || NB == 1) break;
  }
  if (need > ws_size) return;
  const size_t RC = (size_t)NB*S_;
  const int NBH = NB*H_, rows = (int)RC;

  float* hbuf = (float*)take(RC*512*4);
  float* ddq  = (float*)take(RC*512*4);   // ddq' ┐ contiguous -> ffn hidden
  float* ddk  = (float*)take(RC*512*4);   // ddk' ┘ (bf16 RC x 2048)
  bf16*  vbf  = (bf16*)take(RC*512*2);
  bf16*  ybf  = (bf16*)take(RC*512*2);
  float* dqmax= (float*)take(RC*8*4);
  float* ctx  = (float*)take((size_t)NBH*4096*4);
  float* kps  = (float*)take((size_t)NBH*64*4);
  unsigned* kmaxU = (unsigned*)take((size_t)NBH*4);
  bf16* hidbf = (bf16*)ddq;

  dim3 blk(256);

  // ---- per-launch weight prep ----
  for (int l=0; l<L_; ++l){
    bf16* Wl = Wcat + (size_t)l*WCAT;
    float* bl = bcat + (size_t)l*2560;
    convT_k<<<dim3(16,16), blk, 0, stream>>>(wq + l*W55, Wl, 512, 512, 0,    128);
    projw_k<<<dim3(8,8),   blk, 0, stream>>>(wq + l*W55, proj + l*4096, Wl, 64);
    convT_k<<<dim3(16,16), blk, 0, stream>>>(wk + l*W55, Wl, 512, 512, 1024, 128);
    projw_k<<<dim3(8,8),   blk, 0, stream>>>(wk + l*W55, proj + l*4096, Wl, 1024+64);
    convT_k<<<dim3(16,16), blk, 0, stream>>>(wv + l*W55, Wl, 512, 512, 2048, 64);
    bpack_k<<<10, blk, 0, stream>>>(bq + l*512, bk + l*512, bv + l*512, proj + l*4096, bl);
    convT_k<<<dim3(16,16), blk, 0, stream>>>(wo + l*W55, woT + l*W55, 512, 512, 0, 64);
    convT_k<<<dim3(64,16), blk, 0, stream>>>(w1 + l*W52, w1T + l*W52, 512, 2048, 0, 64);
    convT_k<<<dim3(16,64), blk, 0, stream>>>(w2 + l*W52, w2T + l*W52, 2048, 512, 0, 64);
  }
  convT_k<<<dim3(16,2), blk, 0, stream>>>(emb_w, embT, 64, 512, 0, 64);
  conv_k<<<(B_*S_*DIN_/4 + 255)/256, blk, 0, stream>>>(x, xbf, B_*S_*DIN_/4);

  const int rg = (rows + 127)/128;

  for (int bc = 0; bc < B_/NB; ++bc){
    const bf16* xc = xbf + (size_t)bc*RC*DIN_;
    float* outc = out + (size_t)bc*NB*2;

    gemm2_k<0,1,0><<<dim3(4, rg), blk, 0, stream>>>(
        xc, embT, emb_b, pos, hbuf, nullptr, rows, 512, 64, S_);

    for (int l=0; l<L_; ++l){
      ln_k<<<2048, blk, 0, stream>>>(hbuf, ln1_g + l*512, ln1_b + l*512, ybf, rows);
      kinit_k<<<(NBH+255)/256, blk, 0, stream>>>(kmaxU, NBH);
      gemm_mega_k<<<dim3(20, rg), blk, 0, stream>>>(
          ybf, Wcat + (size_t)l*WCAT, bcat + (size_t)l*2560, rows,
          ddq, ddk, vbf, dqmax, kmaxU);
      fctx_k<<<NBH, blk, 0, stream>>>(ddk, vbf, kmaxU, ctx, kps);
      attnout_k<<<dim3(NBH, (S_+63)/64), blk, 0, stream>>>(ddq, dqmax, ctx, kps, ybf);
      gemm2_k<0,1,0><<<dim3(4, rg), blk, 0, stream>>>(
          ybf, woT + l*W55, bo + l*512, hbuf, hbuf, nullptr, rows, 512, 512, 0);
      ln_k<<<2048, blk, 0, stream>>>(hbuf, ln2_g + l*512, ln2_b + l*512, ybf, rows);
      gemm2_k<1,0,1><<<dim3(16, rg), blk, 0, stream>>>(
          ybf, w1T + l*W52, b1 + l*2048, nullptr, nullptr, hidbf, rows, 2048, 512, 0);
      gemm2_k<0,1,0><<<dim3(4, rg), blk, 0, stream>>>(
          hidbf, w2T + l*W52, b2 + l*512, hbuf, hbuf, nullptr, rows, 512, 2048, 0);
    }
    head_k<<<NB, blk, 0, stream>>>(hbuf, fc_w, fc_b, outc);
  }
}

// Round 6
// 4821.121 us; speedup vs baseline: 1.0113x; 1.0113x over previous
//
#include <hip/hip_runtime.h>
#include <hip/hip_bf16.h>

#define B_   64
#define S_   800
#define DIN_ 64
#define D_   512
#define H_   8
#define DH_  64
#define M_   64
#define L_   2
#define FF_  2048

typedef __hip_bfloat16 bf16;
typedef __attribute__((ext_vector_type(8))) short bf16x8;
typedef __attribute__((ext_vector_type(4))) float f32x4;

#define NORM_ 0.35355339059327373f   // 64^(-1/4)

__device__ __forceinline__ unsigned flipf(float f){
  unsigned u = __float_as_uint(f);
  return u ^ (((unsigned)((int)u >> 31)) | 0x80000000u);
}
__device__ __forceinline__ float unflipf(unsigned u){
  unsigned b = (u & 0x80000000u) ? (u ^ 0x80000000u) : ~u;
  return __uint_as_float(b);
}
__device__ __forceinline__ float gelu_f(float x){
  float x3 = x*x*x;
  return 0.5f*x*(1.f + tanhf(0.7978845608028654f*(x + 0.044715f*x3)));
}
__device__ __forceinline__ void st_bf4(bf16* p, float4 v){
  union { bf16 b[4]; unsigned long long u; } q;
  q.b[0]=__float2bfloat16(v.x); q.b[1]=__float2bfloat16(v.y);
  q.b[2]=__float2bfloat16(v.z); q.b[3]=__float2bfloat16(v.w);
  *(unsigned long long*)p = q.u;
}
__device__ __forceinline__ void gld16(const void* g, void* l){
  __builtin_amdgcn_global_load_lds((const __attribute__((address_space(1))) void*)g,
                                   (__attribute__((address_space(3))) void*)l, 16, 0, 0);
}

// ---------------- shared MFMA tile core: dbuf prefetch (T3-min) + T2 swz ---
// A bf16 [rows][K], Wt bf16 [N][K]. 128x128 tile, BK=32, 256 thr = 4 waves.
// Double-buffered LDS; next K-step's global_load_lds issued BEFORE current
// step's ds_read+MFMA; ONE __syncthreads per step (drains vmcnt+lgkm).
// Chunk-XOR swizzle: LDS chunk p of row r holds global chunk p^((r>>1)&3)
// (write: pre-swizzled global source; read: same XOR) -> conflict-free.
__device__ __forceinline__ void gemm_tile(const bf16* __restrict__ A,
                                          const bf16* __restrict__ Wt,
                                          int rows, int K, f32x4 (&acc)[4][4])
{
  __shared__ bf16 As[2][128*32];
  __shared__ bf16 Bs[2][128*32];
  const int tid = threadIdx.x, wave = tid>>6, lane = tid&63;
  const int row0 = blockIdx.y*128, col0 = blockIdx.x*128;
  const int wm = (wave>>1)*64, wn = (wave&1)*64;
  const int lr = lane&15;
  const int lk = ((lane>>4) ^ ((lane>>1)&3))*8;       // swizzled read offset
  const int c0 = wave*2, c1 = c0+1;
  const int sub = lane>>2;
  const int kq = (((lane&3) ^ ((lane>>3)&3)))*8;      // swizzled source chunk
  const int ra0 = min(row0 + c0*16 + sub, rows-1);
  const int ra1 = min(row0 + c1*16 + sub, rows-1);
  const bf16* gA0 = A + (size_t)ra0*K + kq;
  const bf16* gA1 = A + (size_t)ra1*K + kq;
  const bf16* gB0 = Wt + (size_t)(col0 + c0*16 + sub)*K + kq;
  const bf16* gB1 = Wt + (size_t)(col0 + c1*16 + sub)*K + kq;
  const int o0 = c0*512, o1 = c1*512;
  const int nt = K>>5;
  // prologue: stage tile 0 into buffer 0
  gld16(gA0, &As[0][o0]);  gld16(gA1, &As[0][o1]);
  gld16(gB0, &Bs[0][o0]);  gld16(gB1, &Bs[0][o1]);
  __syncthreads();
  int cur = 0;
  for (int t=0; t<nt; ++t){
    const int nxt = cur^1;
    if (t+1 < nt){
      const int k0 = (t+1)*32;
      gld16(gA0 + k0, &As[nxt][o0]);  gld16(gA1 + k0, &As[nxt][o1]);
      gld16(gB0 + k0, &Bs[nxt][o0]);  gld16(gB1 + k0, &Bs[nxt][o1]);
    }
    bf16x8 af[4], bv[4];
    #pragma unroll
    for (int mi=0;mi<4;mi++) af[mi] = *(const bf16x8*)&As[cur][(wm+mi*16+lr)*32 + lk];
    #pragma unroll
    for (int ni=0;ni<4;ni++) bv[ni] = *(const bf16x8*)&Bs[cur][(wn+ni*16+lr)*32 + lk];
    #pragma unroll
    for (int mi=0;mi<4;mi++)
      #pragma unroll
      for (int ni=0;ni<4;ni++)
        acc[mi][ni] = __builtin_amdgcn_mfma_f32_16x16x32_bf16(af[mi], bv[ni], acc[mi][ni], 0,0,0);
    __syncthreads();    // drains this step's prefetch + all ds_reads
    cur = nxt;
  }
}

// ---------------- standard GEMM: C = act(A@W + bias) (+res) ----------------
template<int ACT, int RES, int OUTB>
__global__ __launch_bounds__(256)
void gemm2_k(const bf16* __restrict__ A, const bf16* __restrict__ Wt,
             const float* __restrict__ bias, const float* __restrict__ res,
             float* __restrict__ Cf, bf16* __restrict__ Cb,
             int rows, int N, int K, int res_mod)
{
  f32x4 acc[4][4];
  #pragma unroll
  for (int i=0;i<4;i++)
    #pragma unroll
    for (int j=0;j<4;j++) acc[i][j] = (f32x4){0.f,0.f,0.f,0.f};
  gemm_tile(A, Wt, rows, K, acc);
  const int tid=threadIdx.x, wave=tid>>6, lane=tid&63;
  const int wm=(wave>>1)*64, wn=(wave&1)*64, lr=lane&15, hi=lane>>4;
  const int row0=blockIdx.y*128, col0=blockIdx.x*128;
  #pragma unroll
  for (int mi=0;mi<4;mi++){
    #pragma unroll
    for (int i=0;i<4;i++){
      const int r = row0 + wm + mi*16 + hi*4 + i;
      if (r >= rows) continue;
      #pragma unroll
      for (int ni=0;ni<4;ni++){
        const int c = col0 + wn + ni*16 + lr;
        float v = acc[mi][ni][i] + bias[c];
        if (ACT) v = gelu_f(v);
        if (RES) v += res[(size_t)(res_mod ? (r % res_mod) : r)*N + c];
        if (OUTB) Cb[(size_t)r*N + c] = __float2bfloat16(v);
        else      Cf[(size_t)r*N + c] = v;
      }
    }
  }
}

// ---------------- mega GEMM: N=2560, per-head interleaved ------------------
// cols: [0,1024)= 8x[q_h|ddq_h], [1024,2048)= 8x[k_h|ddk_h], [2048,2560)= v
// q/k-waves (wn==0): diag into LDS. dd-waves (wn==64):
//   q: qp = 0.125*(exp(dd - diag - rowmax)+eps) stored DIRECTLY (fp32)
//   k: store dd-diag; global per-(b,h) max via flipped-uint atomicMax
// v-blocks store bf16.
__global__ __launch_bounds__(256)
void gemm_mega_k(const bf16* __restrict__ A, const bf16* __restrict__ Wcat,
                 const float* __restrict__ bcat, int rows,
                 float* __restrict__ qpb, float* __restrict__ ddk,
                 bf16* __restrict__ vbf, unsigned* __restrict__ kmaxU)
{
  __shared__ float diagL[128];
  f32x4 acc[4][4];
  #pragma unroll
  for (int i=0;i<4;i++)
    #pragma unroll
    for (int j=0;j<4;j++) acc[i][j] = (f32x4){0.f,0.f,0.f,0.f};
  gemm_tile(A, Wcat, rows, 512, acc);
  const int tid=threadIdx.x, wave=tid>>6, lane=tid&63;
  const int wm=(wave>>1)*64, wn=(wave&1)*64, lr=lane&15, hi=lane>>4;
  const int row0 = blockIdx.y*128;
  const int x = blockIdx.x;
  if (x < 16){
    const int isK = x>>3, h = x&7;
    const int cbase = x*128 + wn;
    if (wn == 0){   // q/k wave: diag = 0.5*NORM^2 * sum(val^2)
      #pragma unroll
      for (int mi=0;mi<4;mi++){
        #pragma unroll
        for (int i=0;i<4;i++){
          float s = 0.f;
          #pragma unroll
          for (int ni=0;ni<4;ni++){
            float v = acc[mi][ni][i] + bcat[cbase + ni*16 + lr];
            s += v*v;
          }
          s += __shfl_xor(s,1); s += __shfl_xor(s,2);
          s += __shfl_xor(s,4); s += __shfl_xor(s,8);
          if (lr==0) diagL[wm + mi*16 + hi*4 + i] = 0.0625f*s;  // 0.5*(1/8)
        }
      }
    }
    __syncthreads();
    if (wn == 64){  // dd wave
      #pragma unroll
      for (int mi=0;mi<4;mi++){
        #pragma unroll
        for (int i=0;i<4;i++){
          const int r = row0 + wm + mi*16 + hi*4 + i;
          float vv[4]; float mx = -3.4e38f;
          #pragma unroll
          for (int ni=0;ni<4;ni++){
            vv[ni] = acc[mi][ni][i] + bcat[cbase + ni*16 + lr];
            mx = fmaxf(mx, vv[ni]);
          }
          mx = fmaxf(mx, __shfl_xor(mx,1)); mx = fmaxf(mx, __shfl_xor(mx,2));
          mx = fmaxf(mx, __shfl_xor(mx,4)); mx = fmaxf(mx, __shfl_xor(mx,8));
          if (r < rows){
            const float dg = diagL[wm + mi*16 + hi*4 + i];
            if (!isK){
              #pragma unroll
              for (int ni=0;ni<4;ni++)
                qpb[(size_t)r*512 + h*64 + ni*16 + lr] =
                    0.125f*(expf(vv[ni] - dg - mx) + 1e-4f);
            } else {
              if (lr==0) atomicMax(&kmaxU[(r/S_)*8 + h], flipf(mx));
              #pragma unroll
              for (int ni=0;ni<4;ni++)
                ddk[(size_t)r*512 + h*64 + ni*16 + lr] = vv[ni] - dg;
            }
          }
        }
      }
    }
  } else {          // v block
    const int colb = (x-16)*128 + wn;
    #pragma unroll
    for (int mi=0;mi<4;mi++){
      #pragma unroll
      for (int i=0;i<4;i++){
        const int r = row0 + wm + mi*16 + hi*4 + i;
        if (r >= rows) continue;
        #pragma unroll
        for (int ni=0;ni<4;ni++){
          const int c = colb + ni*16 + lr;
          vbf[(size_t)r*512 + c] = __float2bfloat16(acc[mi][ni][i] + bcat[2048 + c]);
        }
      }
    }
  }
}

// ------- weight transpose+convert with column remap ------------------------
// src f32 [K][N] -> dst rows: row(n) = mapbase + (n>>6)*mapstride + (n&63)
__global__ __launch_bounds__(256)
void convT_k(const float* __restrict__ src, bf16* __restrict__ dst, int K, int N,
             int mapbase, int mapstride)
{
  __shared__ float t[32][33];
  const int n0 = blockIdx.x*32, k0 = blockIdx.y*32;
  const int j = threadIdx.x&31, i0 = threadIdx.x>>5;
  #pragma unroll
  for (int i=i0; i<32; i+=8) t[i][j] = src[(size_t)(k0+i)*N + n0 + j];
  __syncthreads();
  #pragma unroll
  for (int i=i0; i<32; i+=8){
    const int n = n0 + i;
    const int rn = mapbase + (n>>6)*mapstride + (n&63);
    dst[(size_t)rn*K + k0 + j] = __float2bfloat16(t[j][i]);
  }
}

__global__ void conv_k(const float* __restrict__ src, bf16* __restrict__ dst, int n4)
{
  int i = blockIdx.x*256 + threadIdx.x;
  if (i < n4){ float4 v = ((const float4*)src)[i]; st_bf4(dst + (size_t)i*4, v); }
}

// folded feature weight into Wcat: out row = mapbase + h*128 + m
__global__ __launch_bounds__(256)
void projw_k(const float* __restrict__ w, const float* __restrict__ proj,
             bf16* __restrict__ Wcat, int mapbase)
{
  __shared__ float pj[64][64];
  __shared__ float wsh[64][65];
  const int h = blockIdx.x, c0 = blockIdx.y*64;
  const int tid = threadIdx.x, lane = tid&63, tg = tid>>6;
  for (int i=tid; i<4096; i+=256) pj[i>>6][i&63] = proj[i];
  for (int i=tg; i<64; i+=4) wsh[i][lane] = w[(size_t)(c0+i)*512 + h*64 + lane];
  __syncthreads();
  float acc[16];
  #pragma unroll
  for (int j=0;j<16;j++) acc[j]=0.f;
  for (int d=0; d<64; ++d){
    float wv = wsh[lane][d];
    #pragma unroll
    for (int j=0;j<16;j++) acc[j] += wv * pj[tg*16+j][d];
  }
  #pragma unroll
  for (int j=0;j<16;j++)
    Wcat[(size_t)(mapbase + h*128 + tg*16 + j)*512 + c0 + lane] = __float2bfloat16(acc[j]*NORM_);
}

// bias pack for the interleaved 2560-col layout
__global__ void bpack_k(const float* __restrict__ bq, const float* __restrict__ bk,
                        const float* __restrict__ bv, const float* __restrict__ proj,
                        float* __restrict__ bl)
{
  int idx = blockIdx.x*256 + threadIdx.x;
  if (idx >= 2560) return;
  float v;
  if (idx < 2048){
    const float* bsrc = (idx<1024)? bq : bk;
    int t = idx & 1023;
    int h = t>>7, w = t&127;
    if (w < 64) v = bsrc[h*64+w];
    else {
      int m = w-64; float acc=0.f;
      for (int d=0; d<64; ++d) acc += bsrc[h*64+d]*proj[m*64+d];
      v = acc*NORM_;
    }
  } else v = bv[idx-2048];
  bl[idx] = v;
}

// ---------------- LayerNorm (grid-stride, bf16 out) ------------------------
__global__ __launch_bounds__(256)
void ln_k(const float* __restrict__ x, const float* __restrict__ g,
          const float* __restrict__ b, bf16* __restrict__ y, int nrows)
{
  const int wid = threadIdx.x>>6, lane = threadIdx.x&63;
  float4 g0 = *(const float4*)(g + lane*4);
  float4 g1 = *(const float4*)(g + 256 + lane*4);
  float4 b0 = *(const float4*)(b + lane*4);
  float4 b1 = *(const float4*)(b + 256 + lane*4);
  for (size_t row = (size_t)blockIdx.x*4 + wid; row < (size_t)nrows; row += (size_t)gridDim.x*4){
    const float* xr = x + row*D_;
    float4 v0 = *(const float4*)(xr + lane*4);
    float4 v1 = *(const float4*)(xr + 256 + lane*4);
    float s  = v0.x+v0.y+v0.z+v0.w + v1.x+v1.y+v1.z+v1.w;
    float ss = v0.x*v0.x+v0.y*v0.y+v0.z*v0.z+v0.w*v0.w
             + v1.x*v1.x+v1.y*v1.y+v1.z*v1.z+v1.w*v1.w;
    #pragma unroll
    for (int o=32;o;o>>=1){ s += __shfl_xor(s,o); ss += __shfl_xor(ss,o); }
    const float mean = s*(1.f/D_);
    const float rstd = rsqrtf(ss*(1.f/D_) - mean*mean + 1e-5f);
    float4 o0, o1;
    o0.x=(v0.x-mean)*rstd*g0.x+b0.x; o0.y=(v0.y-mean)*rstd*g0.y+b0.y;
    o0.z=(v0.z-mean)*rstd*g0.z+b0.z; o0.w=(v0.w-mean)*rstd*g0.w+b0.w;
    o1.x=(v1.x-mean)*rstd*g1.x+b1.x; o1.y=(v1.y-mean)*rstd*g1.y+b1.y;
    o1.z=(v1.z-mean)*rstd*g1.z+b1.z; o1.w=(v1.w-mean)*rstd*g1.w+b1.w;
    bf16* yr = y + row*D_;
    st_bf4(yr + lane*4, o0);
    st_bf4(yr + 256 + lane*4, o1);
  }
}

__global__ void kinit_k(unsigned* __restrict__ kmax, int n){
  int i = blockIdx.x*256 + threadIdx.x;
  if (i < n) kmax[i] = 0u;   // flipped-float identity
}

// ------- fused featK + kps + ctx: per-(b,h) block --------------------------
// kp[s][m] = 0.125*(exp(ddk'[s][m] - stab)+eps) computed on the fly;
// ctx[m][d] += kp[s][m]*v[s][d];  kps[m] = sum_s kp[s][m].  kp never stored.
__global__ __launch_bounds__(256)
void fctx_k(const float* __restrict__ ddk, const bf16* __restrict__ vbf,
            const unsigned* __restrict__ kmaxU,
            float* __restrict__ ctx, float* __restrict__ kps)
{
  __shared__ float kc[32][64], vc[32][64];
  const int bh = blockIdx.x, tid = threadIdx.x;
  const int b = bh>>3, h = bh&7;
  const float stab = unflipf(kmaxU[bh]);
  const int mq = tid>>4, dq = tid&15;
  const int cc = (tid&15)*4;
  float acc[4][4];
  #pragma unroll
  for (int i=0;i<4;i++)
    #pragma unroll
    for (int j=0;j<4;j++) acc[i][j]=0.f;
  float kpart[4] = {0.f,0.f,0.f,0.f};
  for (int s0=0; s0<S_; s0+=32){
    #pragma unroll
    for (int ii=0; ii<2; ++ii){
      const int rr = (tid>>4) + ii*16;
      const size_t grow = (size_t)(b*S_+s0+rr)*512 + h*64 + cc;
      float4 d4 = *(const float4*)(ddk + grow);
      float4 kv;
      kv.x = 0.125f*(expf(d4.x - stab)+1e-4f);
      kv.y = 0.125f*(expf(d4.y - stab)+1e-4f);
      kv.z = 0.125f*(expf(d4.z - stab)+1e-4f);
      kv.w = 0.125f*(expf(d4.w - stab)+1e-4f);
      *(float4*)&kc[rr][cc] = kv;
      kpart[0]+=kv.x; kpart[1]+=kv.y; kpart[2]+=kv.z; kpart[3]+=kv.w;
      const bf16* vp = vbf + grow;
      float4 vv;
      vv.x = __bfloat162float(vp[0]); vv.y = __bfloat162float(vp[1]);
      vv.z = __bfloat162float(vp[2]); vv.w = __bfloat162float(vp[3]);
      *(float4*)&vc[rr][cc] = vv;
    }
    __syncthreads();
    #pragma unroll 8
    for (int ssi=0; ssi<32; ++ssi){
      float a0=kc[ssi][mq*4+0],a1=kc[ssi][mq*4+1],a2=kc[ssi][mq*4+2],a3=kc[ssi][mq*4+3];
      float b0=vc[ssi][dq*4+0],b1=vc[ssi][dq*4+1],b2=vc[ssi][dq*4+2],b3=vc[ssi][dq*4+3];
      acc[0][0]+=a0*b0; acc[0][1]+=a0*b1; acc[0][2]+=a0*b2; acc[0][3]+=a0*b3;
      acc[1][0]+=a1*b0; acc[1][1]+=a1*b1; acc[1][2]+=a1*b2; acc[1][3]+=a1*b3;
      acc[2][0]+=a2*b0; acc[2][1]+=a2*b1; acc[2][2]+=a2*b2; acc[2][3]+=a2*b3;
      acc[3][0]+=a3*b0; acc[3][1]+=a3*b1; acc[3][2]+=a3*b2; acc[3][3]+=a3*b3;
    }
    __syncthreads();
  }
  #pragma unroll
  for (int i=0;i<4;i++)
    #pragma unroll
    for (int j=0;j<4;j++)
      ctx[((size_t)bh*64 + mq*4+i)*64 + dq*4+j] = acc[i][j];
  // kps reduce: thread t held cols (t&15)*4+j
  float* kcf = &kc[0][0];
  #pragma unroll
  for (int j=0;j<4;j++) kcf[tid*4+j] = kpart[j];
  __syncthreads();
  if (tid < 64){
    const int m = tid;
    float s = 0.f;
    #pragma unroll
    for (int g=0; g<16; ++g) s += kcf[(g*16 + (m>>2))*4 + (m&3)];
    kps[bh*64 + m] = s;
  }
}

// ------- attn out: qp read directly (precomputed in mega epilogue) ---------
__global__ __launch_bounds__(256)
void attnout_k(const float* __restrict__ qpb, const float* __restrict__ ctx,
               const float* __restrict__ kps, bf16* __restrict__ out)
{
  __shared__ float cl[4096];
  __shared__ float kl[64];
  __shared__ float qL[4][64];
  const int bh = blockIdx.x, tid = threadIdx.x;
  for (int i=tid;i<4096;i+=256) cl[i] = ctx[(size_t)bh*4096 + i];
  if (tid<64) kl[tid] = kps[bh*64+tid];
  const int b = bh>>3, h = bh&7;
  const int d = tid&63, sg = tid>>6;
  const int send = min((int)(blockIdx.y*64+64), S_);
  for (int s0 = blockIdx.y*64; s0 < send; s0 += 4){
    const int sr = s0 + sg;
    const size_t rrow = (size_t)(b*S_+sr);
    float qp = qpb[rrow*512 + h*64 + d];
    __syncthreads();
    qL[sg][d] = qp;
    __syncthreads();
    float a0=0,a1=0,a2=0,a3=0, e0=0,e1=0,e2=0,e3=0;
    #pragma unroll
    for (int m=0;m<64;m+=4){
      float q0=qL[sg][m], q1=qL[sg][m+1], q2=qL[sg][m+2], q3=qL[sg][m+3];
      a0 += q0*cl[(m  )*64+d]; a1 += q1*cl[(m+1)*64+d];
      a2 += q2*cl[(m+2)*64+d]; a3 += q3*cl[(m+3)*64+d];
      e0 += q0*kl[m]; e1 += q1*kl[m+1]; e2 += q2*kl[m+2]; e3 += q3*kl[m+3];
    }
    const float den = (e0+e1)+(e2+e3);
    const float o = ((a0+a1)+(a2+a3))/den;
    out[(rrow*H_ + h)*64 + d] = __float2bfloat16(o);
  }
}

// ---------------- head ----------------------------------------------------
__global__ __launch_bounds__(256)
void head_k(const float* __restrict__ h, const float* __restrict__ fcw,
            const float* __restrict__ fcb, float* __restrict__ out)
{
  __shared__ float red[256][2];
  const int b = blockIdx.x, tid = threadIdx.x;
  const float* hb = h + (size_t)b*S_*D_;
  float s0=0.f, s1=0.f;
  for (int s=0; s<S_; ++s){
    s0 += hb[(size_t)s*D_ + tid];
    s1 += hb[(size_t)s*D_ + tid + 256];
  }
  const float m0 = s0*(1.f/S_), m1 = s1*(1.f/S_);
  red[tid][0] = m0*fcw[tid*2+0] + m1*fcw[(tid+256)*2+0];
  red[tid][1] = m0*fcw[tid*2+1] + m1*fcw[(tid+256)*2+1];
  __syncthreads();
  for (int st=128; st; st>>=1){
    if (tid<st){ red[tid][0]+=red[tid+st][0]; red[tid][1]+=red[tid+st][1]; }
    __syncthreads();
  }
  if (tid==0){ out[b*2+0]=red[0][0]+fcb[0]; out[b*2+1]=red[0][1]+fcb[1]; }
}

extern "C" void kernel_launch(void* const* d_in, const int* in_sizes, int n_in,
                              void* d_out, int out_size, void* d_ws, size_t ws_size,
                              hipStream_t stream)
{
  const float* x     = (const float*)d_in[0];
  const float* emb_w = (const float*)d_in[1];
  const float* emb_b = (const float*)d_in[2];
  const float* pos   = (const float*)d_in[3];
  const float* ln1_g = (const float*)d_in[4];
  const float* ln1_b = (const float*)d_in[5];
  const float* wq    = (const float*)d_in[6];
  const float* bq    = (const float*)d_in[7];
  const float* wk    = (const float*)d_in[8];
  const float* bk    = (const float*)d_in[9];
  const float* wv    = (const float*)d_in[10];
  const float* bv    = (const float*)d_in[11];
  const float* wo    = (const float*)d_in[12];
  const float* bo    = (const float*)d_in[13];
  const float* proj  = (const float*)d_in[14];
  const float* ln2_g = (const float*)d_in[15];
  const float* ln2_b = (const float*)d_in[16];
  const float* w1    = (const float*)d_in[17];
  const float* b1    = (const float*)d_in[18];
  const float* w2    = (const float*)d_in[19];
  const float* b2    = (const float*)d_in[20];
  const float* fc_w  = (const float*)d_in[21];
  const float* fc_b  = (const float*)d_in[22];
  float* out = (float*)d_out;

  const size_t W55 = (size_t)512*512, W52 = (size_t)512*2048;
  const size_t WCAT = (size_t)2560*512;

  char* p = (char*)d_ws;
  auto take = [&](size_t bytes)->char*{
    char* r = p; p += (bytes + 255) & ~(size_t)255; return r;
  };
  bf16* Wcat = (bf16*)take(L_*WCAT*2);
  bf16* woT  = (bf16*)take(L_*W55*2);
  bf16* w1T  = (bf16*)take(L_*W52*2);
  bf16* w2T  = (bf16*)take(L_*W52*2);
  bf16* embT = (bf16*)take((size_t)64*512*2);
  bf16* xbf  = (bf16*)take((size_t)B_*S_*DIN_*2);
  float* bcat= (float*)take(L_*2560*4);
  const size_t fixed_bytes = (size_t)(p - (char*)d_ws);

  int NB = 64; size_t need = 0;
  for (;; NB >>= 1){
    size_t RC = (size_t)NB*S_, nbh = (size_t)NB*H_;
    need = fixed_bytes + RC*8192 + nbh*(16384+256+4) + 65536;
    if (need <= ws_size || NB == 1) break;
  }
  if (need > ws_size) return;
  const size_t RC = (size_t)NB*S_;
  const int NBH = NB*H_, rows = (int)RC;

  float* hbuf = (float*)take(RC*512*4);
  float* qpb  = (float*)take(RC*512*4);   // qp   ┐ contiguous -> ffn hidden
  float* ddk  = (float*)take(RC*512*4);   // ddk' ┘ (bf16 RC x 2048)
  bf16*  vbf  = (bf16*)take(RC*512*2);
  bf16*  ybf  = (bf16*)take(RC*512*2);
  float* ctx  = (float*)take((size_t)NBH*4096*4);
  float* kps  = (float*)take((size_t)NBH*64*4);
  unsigned* kmaxU = (unsigned*)take((size_t)NBH*4);
  bf16* hidbf = (bf16*)qpb;

  dim3 blk(256);

  // ---- per-launch weight prep ----
  for (int l=0; l<L_; ++l){
    bf16* Wl = Wcat + (size_t)l*WCAT;
    float* bl = bcat + (size_t)l*2560;
    convT_k<<<dim3(16,16), blk, 0, stream>>>(wq + l*W55, Wl, 512, 512, 0,    128);
    projw_k<<<dim3(8,8),   blk, 0, stream>>>(wq + l*W55, proj + l*4096, Wl, 64);
    convT_k<<<dim3(16,16), blk, 0, stream>>>(wk + l*W55, Wl, 512, 512, 1024, 128);
    projw_k<<<dim3(8,8),   blk, 0, stream>>>(wk + l*W55, proj + l*4096, Wl, 1024+64);
    convT_k<<<dim3(16,16), blk, 0, stream>>>(wv + l*W55, Wl, 512, 512, 2048, 64);
    bpack_k<<<10, blk, 0, stream>>>(bq + l*512, bk + l*512, bv + l*512, proj + l*4096, bl);
    convT_k<<<dim3(16,16), blk, 0, stream>>>(wo + l*W55, woT + l*W55, 512, 512, 0, 64);
    convT_k<<<dim3(64,16), blk, 0, stream>>>(w1 + l*W52, w1T + l*W52, 512, 2048, 0, 64);
    convT_k<<<dim3(16,64), blk, 0, stream>>>(w2 + l*W52, w2T + l*W52, 2048, 512, 0, 64);
  }
  convT_k<<<dim3(16,2), blk, 0, stream>>>(emb_w, embT, 64, 512, 0, 64);
  conv_k<<<(B_*S_*DIN_/4 + 255)/256, blk, 0, stream>>>(x, xbf, B_*S_*DIN_/4);

  const int rg = (rows + 127)/128;

  for (int bc = 0; bc < B_/NB; ++bc){
    const bf16* xc = xbf + (size_t)bc*RC*DIN_;
    float* outc = out + (size_t)bc*NB*2;

    gemm2_k<0,1,0><<<dim3(4, rg), blk, 0, stream>>>(
        xc, embT, emb_b, pos, hbuf, nullptr, rows, 512, 64, S_);

    for (int l=0; l<L_; ++l){
      ln_k<<<2048, blk, 0, stream>>>(hbuf, ln1_g + l*512, ln1_b + l*512, ybf, rows);
      kinit_k<<<(NBH+255)/256, blk, 0, stream>>>(kmaxU, NBH);
      gemm_mega_k<<<dim3(20, rg), blk, 0, stream>>>(
          ybf, Wcat + (size_t)l*WCAT, bcat + (size_t)l*2560, rows,
          qpb, ddk, vbf, kmaxU);
      fctx_k<<<NBH, blk, 0, stream>>>(ddk, vbf, kmaxU, ctx, kps);
      attnout_k<<<dim3(NBH, (S_+63)/64), blk, 0, stream>>>(qpb, ctx, kps, ybf);
      gemm2_k<0,1,0><<<dim3(4, rg), blk, 0, stream>>>(
          ybf, woT + l*W55, bo + l*512, hbuf, hbuf, nullptr, rows, 512, 512, 0);
      ln_k<<<2048, blk, 0, stream>>>(hbuf, ln2_g + l*512, ln2_b + l*512, ybf, rows);
      gemm2_k<1,0,1><<<dim3(16, rg), blk, 0, stream>>>(
          ybf, w1T + l*W52, b1 + l*2048, nullptr, nullptr, hidbf, rows, 2048, 512, 0);
      gemm2_k<0,1,0><<<dim3(4, rg), blk, 0, stream>>>(
          hidbf, w2T + l*W52, b2 + l*512, hbuf, hbuf, nullptr, rows, 512, 2048, 0);
    }
    head_k<<<NB, blk, 0, stream>>>(hbuf, fc_w, fc_b, outc);
  }
}

// Round 7
// 4100.346 us; speedup vs baseline: 1.1891x; 1.1758x over previous
//
#include <hip/hip_runtime.h>
#include <hip/hip_bf16.h>

#define B_   64
#define S_   800
#define DIN_ 64
#define D_   512
#define H_   8
#define DH_  64
#define M_   64
#define L_   2
#define FF_  2048

typedef __hip_bfloat16 bf16;
typedef __attribute__((ext_vector_type(8))) short bf16x8;
typedef __attribute__((ext_vector_type(4))) float f32x4;

#define NORM_ 0.35355339059327373f   // 64^(-1/4)

__device__ __forceinline__ unsigned flipf(float f){
  unsigned u = __float_as_uint(f);
  return u ^ (((unsigned)((int)u >> 31)) | 0x80000000u);
}
__device__ __forceinline__ float unflipf(unsigned u){
  unsigned b = (u & 0x80000000u) ? (u ^ 0x80000000u) : ~u;
  return __uint_as_float(b);
}
__device__ __forceinline__ float gelu_f(float x){
  float x3 = x*x*x;
  return 0.5f*x*(1.f + tanhf(0.7978845608028654f*(x + 0.044715f*x3)));
}
__device__ __forceinline__ void st_bf4(bf16* p, float4 v){
  union { bf16 b[4]; unsigned long long u; } q;
  q.b[0]=__float2bfloat16(v.x); q.b[1]=__float2bfloat16(v.y);
  q.b[2]=__float2bfloat16(v.z); q.b[3]=__float2bfloat16(v.w);
  *(unsigned long long*)p = q.u;
}
__device__ __forceinline__ void gld16(const void* g, void* l){
  __builtin_amdgcn_global_load_lds((const __attribute__((address_space(1))) void*)g,
                                   (__attribute__((address_space(3))) void*)l, 16, 0, 0);
}

// XCD-chunked bijective block swizzle (m204): consecutive logical blocks
// stay on one XCD -> A-panel L2 reuse.
__device__ __forceinline__ void swz_xy(int gx, int& bx, int& by){
  const int nwg = (int)gridDim.x, orig = (int)blockIdx.x;
  const int q = nwg>>3, r = nwg&7;
  const int xcd = orig&7, lin = orig>>3;
  const int wg = (xcd<r ? xcd*(q+1) : r*(q+1)+(xcd-r)*q) + lin;
  bx = wg % gx;  by = wg / gx;
}

// ---------------- MFMA tile core: depth-2 pipeline, counted vmcnt ----------
// A bf16 [rows][K], Wt bf16 [N][K]. 128x128 tile, BK=32, 256 thr = 4 waves.
// 3 LDS buffers; per iter: ds_read(cur) -> stage(t+2) -> MFMA ->
// s_waitcnt vmcnt(4) -> raw s_barrier.  Loads stay in flight across
// barriers (T3+T4); vmcnt(4) = newest stage group outstanding, tile t+1
// guaranteed landed.  Chunk-XOR swizzle (T2) as before: LDS chunk p of
// row r holds global chunk p^((r>>1)&3), read with same XOR.
__device__ __forceinline__ void gemm_tile(const bf16* __restrict__ A,
                                          const bf16* __restrict__ Wt,
                                          int rows, int K, int bx, int by,
                                          f32x4 (&acc)[4][4])
{
  __shared__ bf16 As[3*4096];
  __shared__ bf16 Bs[3*4096];
  const int tid = threadIdx.x, wave = tid>>6, lane = tid&63;
  const int row0 = by*128, col0 = bx*128;
  const int wm = (wave>>1)*64, wn = (wave&1)*64;
  const int lr = lane&15;
  const int lk = ((lane>>4) ^ ((lane>>1)&3))*8;       // swizzled read offset
  const int c0 = wave*2, c1 = c0+1;
  const int sub = lane>>2;
  const int kq = (((lane&3) ^ ((lane>>3)&3)))*8;      // swizzled source chunk
  const int ra0 = min(row0 + c0*16 + sub, rows-1);
  const int ra1 = min(row0 + c1*16 + sub, rows-1);
  const bf16* gA0 = A + (size_t)ra0*K + kq;
  const bf16* gA1 = A + (size_t)ra1*K + kq;
  const bf16* gB0 = Wt + (size_t)(col0 + c0*16 + sub)*K + kq;
  const bf16* gB1 = Wt + (size_t)(col0 + c1*16 + sub)*K + kq;
  const int o0 = c0*512, o1 = c1*512;
  const int nt = K>>5;
  // prologue: stage tiles 0 and 1
  gld16(gA0, &As[o0]);  gld16(gA1, &As[o1]);
  gld16(gB0, &Bs[o0]);  gld16(gB1, &Bs[o1]);
  if (nt > 1){
    gld16(gA0+32, &As[4096+o0]);  gld16(gA1+32, &As[4096+o1]);
    gld16(gB0+32, &Bs[4096+o0]);  gld16(gB1+32, &Bs[4096+o1]);
    asm volatile("s_waitcnt vmcnt(4)" ::: "memory");   // tile 0 landed
  } else {
    asm volatile("s_waitcnt vmcnt(0)" ::: "memory");
  }
  __builtin_amdgcn_s_barrier();
  __builtin_amdgcn_sched_barrier(0);
  int rdofs = 0;       // current read buffer offset (elements)
  int stofs = 8192;    // next stage slot offset
  for (int t=0; t<nt; ++t){
    bf16x8 af[4], bv[4];
    #pragma unroll
    for (int mi=0;mi<4;mi++) af[mi] = *(const bf16x8*)&As[rdofs + (wm+mi*16+lr)*32 + lk];
    #pragma unroll
    for (int ni=0;ni<4;ni++) bv[ni] = *(const bf16x8*)&Bs[rdofs + (wn+ni*16+lr)*32 + lk];
    if (t+2 < nt){
      const int k0 = (t+2)*32;
      gld16(gA0+k0, &As[stofs+o0]);  gld16(gA1+k0, &As[stofs+o1]);
      gld16(gB0+k0, &Bs[stofs+o0]);  gld16(gB1+k0, &Bs[stofs+o1]);
      stofs = (stofs==8192)?0:stofs+4096;
    }
    #pragma unroll
    for (int mi=0;mi<4;mi++)
      #pragma unroll
      for (int ni=0;ni<4;ni++)
        acc[mi][ni] = __builtin_amdgcn_mfma_f32_16x16x32_bf16(af[mi], bv[ni], acc[mi][ni], 0,0,0);
    rdofs = (rdofs==8192)?0:rdofs+4096;
    if (t+1 < nt){
      if (t+2 < nt) asm volatile("s_waitcnt vmcnt(4)" ::: "memory");
      else          asm volatile("s_waitcnt vmcnt(0)" ::: "memory");
      __builtin_amdgcn_s_barrier();
      __builtin_amdgcn_sched_barrier(0);
    }
  }
}

// ---------------- standard GEMM: C = act(A@W + bias) (+res) ----------------
template<int ACT, int RES, int OUTB>
__global__ __launch_bounds__(256)
void gemm2_k(const bf16* __restrict__ A, const bf16* __restrict__ Wt,
             const float* __restrict__ bias, const float* __restrict__ res,
             float* __restrict__ Cf, bf16* __restrict__ Cb,
             int rows, int N, int K, int res_mod, int gx)
{
  int bx, by;  swz_xy(gx, bx, by);
  f32x4 acc[4][4];
  #pragma unroll
  for (int i=0;i<4;i++)
    #pragma unroll
    for (int j=0;j<4;j++) acc[i][j] = (f32x4){0.f,0.f,0.f,0.f};
  gemm_tile(A, Wt, rows, K, bx, by, acc);
  const int tid=threadIdx.x, wave=tid>>6, lane=tid&63;
  const int wm=(wave>>1)*64, wn=(wave&1)*64, lr=lane&15, hi=lane>>4;
  const int row0=by*128, col0=bx*128;
  #pragma unroll
  for (int mi=0;mi<4;mi++){
    #pragma unroll
    for (int i=0;i<4;i++){
      const int r = row0 + wm + mi*16 + hi*4 + i;
      if (r >= rows) continue;
      #pragma unroll
      for (int ni=0;ni<4;ni++){
        const int c = col0 + wn + ni*16 + lr;
        float v = acc[mi][ni][i] + bias[c];
        if (ACT) v = gelu_f(v);
        if (RES) v += res[(size_t)(res_mod ? (r % res_mod) : r)*N + c];
        if (OUTB) Cb[(size_t)r*N + c] = __float2bfloat16(v);
        else      Cf[(size_t)r*N + c] = v;
      }
    }
  }
}

// ---------------- mega GEMM: N=2560, per-head interleaved ------------------
// cols: [0,1024)= 8x[q_h|ddq_h], [1024,2048)= 8x[k_h|ddk_h], [2048,2560)= v
// q/k-waves (wn==0): diag into LDS. dd-waves (wn==64):
//   q: qp = 0.125*(exp(dd - diag - rowmax)+eps) stored DIRECTLY (bf16)
//   k: store dd-diag (fp32); global per-(b,h) max via flipped-uint atomicMax
// v-blocks store bf16.
__global__ __launch_bounds__(256)
void gemm_mega_k(const bf16* __restrict__ A, const bf16* __restrict__ Wcat,
                 const float* __restrict__ bcat, int rows,
                 bf16* __restrict__ qpb, float* __restrict__ ddk,
                 bf16* __restrict__ vbf, unsigned* __restrict__ kmaxU, int gx)
{
  __shared__ float diagL[128];
  int x, by;  swz_xy(gx, x, by);
  f32x4 acc[4][4];
  #pragma unroll
  for (int i=0;i<4;i++)
    #pragma unroll
    for (int j=0;j<4;j++) acc[i][j] = (f32x4){0.f,0.f,0.f,0.f};
  gemm_tile(A, Wcat, rows, 512, x, by, acc);
  const int tid=threadIdx.x, wave=tid>>6, lane=tid&63;
  const int wm=(wave>>1)*64, wn=(wave&1)*64, lr=lane&15, hi=lane>>4;
  const int row0 = by*128;
  if (x < 16){
    const int isK = x>>3, h = x&7;
    const int cbase = x*128 + wn;
    if (wn == 0){   // q/k wave: diag = 0.5*NORM^2 * sum(val^2)
      #pragma unroll
      for (int mi=0;mi<4;mi++){
        #pragma unroll
        for (int i=0;i<4;i++){
          float s = 0.f;
          #pragma unroll
          for (int ni=0;ni<4;ni++){
            float v = acc[mi][ni][i] + bcat[cbase + ni*16 + lr];
            s += v*v;
          }
          s += __shfl_xor(s,1); s += __shfl_xor(s,2);
          s += __shfl_xor(s,4); s += __shfl_xor(s,8);
          if (lr==0) diagL[wm + mi*16 + hi*4 + i] = 0.0625f*s;  // 0.5*(1/8)
        }
      }
    }
    __syncthreads();
    if (wn == 64){  // dd wave
      #pragma unroll
      for (int mi=0;mi<4;mi++){
        #pragma unroll
        for (int i=0;i<4;i++){
          const int r = row0 + wm + mi*16 + hi*4 + i;
          float vv[4]; float mx = -3.4e38f;
          #pragma unroll
          for (int ni=0;ni<4;ni++){
            vv[ni] = acc[mi][ni][i] + bcat[cbase + ni*16 + lr];
            mx = fmaxf(mx, vv[ni]);
          }
          mx = fmaxf(mx, __shfl_xor(mx,1)); mx = fmaxf(mx, __shfl_xor(mx,2));
          mx = fmaxf(mx, __shfl_xor(mx,4)); mx = fmaxf(mx, __shfl_xor(mx,8));
          if (r < rows){
            const float dg = diagL[wm + mi*16 + hi*4 + i];
            if (!isK){
              #pragma unroll
              for (int ni=0;ni<4;ni++)
                qpb[(size_t)r*512 + h*64 + ni*16 + lr] =
                    __float2bfloat16(0.125f*(expf(vv[ni] - dg - mx) + 1e-4f));
            } else {
              if (lr==0) atomicMax(&kmaxU[(r/S_)*8 + h], flipf(mx));
              #pragma unroll
              for (int ni=0;ni<4;ni++)
                ddk[(size_t)r*512 + h*64 + ni*16 + lr] = vv[ni] - dg;
            }
          }
        }
      }
    }
  } else {          // v block
    const int colb = (x-16)*128 + wn;
    #pragma unroll
    for (int mi=0;mi<4;mi++){
      #pragma unroll
      for (int i=0;i<4;i++){
        const int r = row0 + wm + mi*16 + hi*4 + i;
        if (r >= rows) continue;
        #pragma unroll
        for (int ni=0;ni<4;ni++){
          const int c = colb + ni*16 + lr;
          vbf[(size_t)r*512 + c] = __float2bfloat16(acc[mi][ni][i] + bcat[2048 + c]);
        }
      }
    }
  }
}

// ------- weight transpose+convert with column remap ------------------------
__global__ __launch_bounds__(256)
void convT_k(const float* __restrict__ src, bf16* __restrict__ dst, int K, int N,
             int mapbase, int mapstride)
{
  __shared__ float t[32][33];
  const int n0 = blockIdx.x*32, k0 = blockIdx.y*32;
  const int j = threadIdx.x&31, i0 = threadIdx.x>>5;
  #pragma unroll
  for (int i=i0; i<32; i+=8) t[i][j] = src[(size_t)(k0+i)*N + n0 + j];
  __syncthreads();
  #pragma unroll
  for (int i=i0; i<32; i+=8){
    const int n = n0 + i;
    const int rn = mapbase + (n>>6)*mapstride + (n&63);
    dst[(size_t)rn*K + k0 + j] = __float2bfloat16(t[j][i]);
  }
}

__global__ void conv_k(const float* __restrict__ src, bf16* __restrict__ dst, int n4)
{
  int i = blockIdx.x*256 + threadIdx.x;
  if (i < n4){ float4 v = ((const float4*)src)[i]; st_bf4(dst + (size_t)i*4, v); }
}

// folded feature weight into Wcat: out row = mapbase + h*128 + m
__global__ __launch_bounds__(256)
void projw_k(const float* __restrict__ w, const float* __restrict__ proj,
             bf16* __restrict__ Wcat, int mapbase)
{
  __shared__ float pj[64][64];
  __shared__ float wsh[64][65];
  const int h = blockIdx.x, c0 = blockIdx.y*64;
  const int tid = threadIdx.x, lane = tid&63, tg = tid>>6;
  for (int i=tid; i<4096; i+=256) pj[i>>6][i&63] = proj[i];
  for (int i=tg; i<64; i+=4) wsh[i][lane] = w[(size_t)(c0+i)*512 + h*64 + lane];
  __syncthreads();
  float acc[16];
  #pragma unroll
  for (int j=0;j<16;j++) acc[j]=0.f;
  for (int d=0; d<64; ++d){
    float wv = wsh[lane][d];
    #pragma unroll
    for (int j=0;j<16;j++) acc[j] += wv * pj[tg*16+j][d];
  }
  #pragma unroll
  for (int j=0;j<16;j++)
    Wcat[(size_t)(mapbase + h*128 + tg*16 + j)*512 + c0 + lane] = __float2bfloat16(acc[j]*NORM_);
}

// bias pack for the interleaved 2560-col layout
__global__ void bpack_k(const float* __restrict__ bq, const float* __restrict__ bk,
                        const float* __restrict__ bv, const float* __restrict__ proj,
                        float* __restrict__ bl)
{
  int idx = blockIdx.x*256 + threadIdx.x;
  if (idx >= 2560) return;
  float v;
  if (idx < 2048){
    const float* bsrc = (idx<1024)? bq : bk;
    int t = idx & 1023;
    int h = t>>7, w = t&127;
    if (w < 64) v = bsrc[h*64+w];
    else {
      int m = w-64; float acc=0.f;
      for (int d=0; d<64; ++d) acc += bsrc[h*64+d]*proj[m*64+d];
      v = acc*NORM_;
    }
  } else v = bv[idx-2048];
  bl[idx] = v;
}

// ---------------- LayerNorm (grid-stride, bf16 out) ------------------------
__global__ __launch_bounds__(256)
void ln_k(const float* __restrict__ x, const float* __restrict__ g,
          const float* __restrict__ b, bf16* __restrict__ y, int nrows)
{
  const int wid = threadIdx.x>>6, lane = threadIdx.x&63;
  float4 g0 = *(const float4*)(g + lane*4);
  float4 g1 = *(const float4*)(g + 256 + lane*4);
  float4 b0 = *(const float4*)(b + lane*4);
  float4 b1 = *(const float4*)(b + 256 + lane*4);
  for (size_t row = (size_t)blockIdx.x*4 + wid; row < (size_t)nrows; row += (size_t)gridDim.x*4){
    const float* xr = x + row*D_;
    float4 v0 = *(const float4*)(xr + lane*4);
    float4 v1 = *(const float4*)(xr + 256 + lane*4);
    float s  = v0.x+v0.y+v0.z+v0.w + v1.x+v1.y+v1.z+v1.w;
    float ss = v0.x*v0.x+v0.y*v0.y+v0.z*v0.z+v0.w*v0.w
             + v1.x*v1.x+v1.y*v1.y+v1.z*v1.z+v1.w*v1.w;
    #pragma unroll
    for (int o=32;o;o>>=1){ s += __shfl_xor(s,o); ss += __shfl_xor(ss,o); }
    const float mean = s*(1.f/D_);
    const float rstd = rsqrtf(ss*(1.f/D_) - mean*mean + 1e-5f);
    float4 o0, o1;
    o0.x=(v0.x-mean)*rstd*g0.x+b0.x; o0.y=(v0.y-mean)*rstd*g0.y+b0.y;
    o0.z=(v0.z-mean)*rstd*g0.z+b0.z; o0.w=(v0.w-mean)*rstd*g0.w+b0.w;
    o1.x=(v1.x-mean)*rstd*g1.x+b1.x; o1.y=(v1.y-mean)*rstd*g1.y+b1.y;
    o1.z=(v1.z-mean)*rstd*g1.z+b1.z; o1.w=(v1.w-mean)*rstd*g1.w+b1.w;
    bf16* yr = y + row*D_;
    st_bf4(yr + lane*4, o0);
    st_bf4(yr + 256 + lane*4, o1);
  }
}

__global__ void kinit_k(unsigned* __restrict__ kmax, int n){
  int i = blockIdx.x*256 + threadIdx.x;
  if (i < n) kmax[i] = 0u;   // flipped-float identity
}

// ------- fused featK + kps + ctx: per-(b,h) block --------------------------
__global__ __launch_bounds__(256)
void fctx_k(const float* __restrict__ ddk, const bf16* __restrict__ vbf,
            const unsigned* __restrict__ kmaxU,
            float* __restrict__ ctx, float* __restrict__ kps)
{
  __shared__ float kc[32][64], vc[32][64];
  const int bh = blockIdx.x, tid = threadIdx.x;
  const int b = bh>>3, h = bh&7;
  const float stab = unflipf(kmaxU[bh]);
  const int mq = tid>>4, dq = tid&15;
  const int cc = (tid&15)*4;
  float acc[4][4];
  #pragma unroll
  for (int i=0;i<4;i++)
    #pragma unroll
    for (int j=0;j<4;j++) acc[i][j]=0.f;
  float kpart[4] = {0.f,0.f,0.f,0.f};
  for (int s0=0; s0<S_; s0+=32){
    #pragma unroll
    for (int ii=0; ii<2; ++ii){
      const int rr = (tid>>4) + ii*16;
      const size_t grow = (size_t)(b*S_+s0+rr)*512 + h*64 + cc;
      float4 d4 = *(const float4*)(ddk + grow);
      float4 kv;
      kv.x = 0.125f*(expf(d4.x - stab)+1e-4f);
      kv.y = 0.125f*(expf(d4.y - stab)+1e-4f);
      kv.z = 0.125f*(expf(d4.z - stab)+1e-4f);
      kv.w = 0.125f*(expf(d4.w - stab)+1e-4f);
      *(float4*)&kc[rr][cc] = kv;
      kpart[0]+=kv.x; kpart[1]+=kv.y; kpart[2]+=kv.z; kpart[3]+=kv.w;
      const bf16* vp = vbf + grow;
      float4 vv;
      vv.x = __bfloat162float(vp[0]); vv.y = __bfloat162float(vp[1]);
      vv.z = __bfloat162float(vp[2]); vv.w = __bfloat162float(vp[3]);
      *(float4*)&vc[rr][cc] = vv;
    }
    __syncthreads();
    #pragma unroll 8
    for (int ssi=0; ssi<32; ++ssi){
      float a0=kc[ssi][mq*4+0],a1=kc[ssi][mq*4+1],a2=kc[ssi][mq*4+2],a3=kc[ssi][mq*4+3];
      float b0=vc[ssi][dq*4+0],b1=vc[ssi][dq*4+1],b2=vc[ssi][dq*4+2],b3=vc[ssi][dq*4+3];
      acc[0][0]+=a0*b0; acc[0][1]+=a0*b1; acc[0][2]+=a0*b2; acc[0][3]+=a0*b3;
      acc[1][0]+=a1*b0; acc[1][1]+=a1*b1; acc[1][2]+=a1*b2; acc[1][3]+=a1*b3;
      acc[2][0]+=a2*b0; acc[2][1]+=a2*b1; acc[2][2]+=a2*b2; acc[2][3]+=a2*b3;
      acc[3][0]+=a3*b0; acc[3][1]+=a3*b1; acc[3][2]+=a3*b2; acc[3][3]+=a3*b3;
    }
    __syncthreads();
  }
  #pragma unroll
  for (int i=0;i<4;i++)
    #pragma unroll
    for (int j=0;j<4;j++)
      ctx[((size_t)bh*64 + mq*4+i)*64 + dq*4+j] = acc[i][j];
  float* kcf = &kc[0][0];
  #pragma unroll
  for (int j=0;j<4;j++) kcf[tid*4+j] = kpart[j];
  __syncthreads();
  if (tid < 64){
    const int m = tid;
    float s = 0.f;
    #pragma unroll
    for (int g=0; g<16; ++g) s += kcf[(g*16 + (m>>2))*4 + (m&3)];
    kps[bh*64 + m] = s;
  }
}

// ------- attn out: qp (bf16, precomputed in mega epilogue) -----------------
__global__ __launch_bounds__(256)
void attnout_k(const bf16* __restrict__ qpb, const float* __restrict__ ctx,
               const float* __restrict__ kps, bf16* __restrict__ out)
{
  __shared__ float cl[4096];
  __shared__ float kl[64];
  __shared__ float qL[4][64];
  const int bh = blockIdx.x, tid = threadIdx.x;
  for (int i=tid;i<4096;i+=256) cl[i] = ctx[(size_t)bh*4096 + i];
  if (tid<64) kl[tid] = kps[bh*64+tid];
  const int b = bh>>3, h = bh&7;
  const int d = tid&63, sg = tid>>6;
  const int send = min((int)(blockIdx.y*64+64), S_);
  for (int s0 = blockIdx.y*64; s0 < send; s0 += 4){
    const int sr = s0 + sg;
    const size_t rrow = (size_t)(b*S_+sr);
    float qp = __bfloat162float(qpb[rrow*512 + h*64 + d]);
    __syncthreads();
    qL[sg][d] = qp;
    __syncthreads();
    float a0=0,a1=0,a2=0,a3=0, e0=0,e1=0,e2=0,e3=0;
    #pragma unroll
    for (int m=0;m<64;m+=4){
      float q0=qL[sg][m], q1=qL[sg][m+1], q2=qL[sg][m+2], q3=qL[sg][m+3];
      a0 += q0*cl[(m  )*64+d]; a1 += q1*cl[(m+1)*64+d];
      a2 += q2*cl[(m+2)*64+d]; a3 += q3*cl[(m+3)*64+d];
      e0 += q0*kl[m]; e1 += q1*kl[m+1]; e2 += q2*kl[m+2]; e3 += q3*kl[m+3];
    }
    const float den = (e0+e1)+(e2+e3);
    const float o = ((a0+a1)+(a2+a3))/den;
    out[(rrow*H_ + h)*64 + d] = __float2bfloat16(o);
  }
}

// ---------------- head ----------------------------------------------------
__global__ __launch_bounds__(256)
void head_k(const float* __restrict__ h, const float* __restrict__ fcw,
            const float* __restrict__ fcb, float* __restrict__ out)
{
  __shared__ float red[256][2];
  const int b = blockIdx.x, tid = threadIdx.x;
  const float* hb = h + (size_t)b*S_*D_;
  float s0=0.f, s1=0.f;
  for (int s=0; s<S_; ++s){
    s0 += hb[(size_t)s*D_ + tid];
    s1 += hb[(size_t)s*D_ + tid + 256];
  }
  const float m0 = s0*(1.f/S_), m1 = s1*(1.f/S_);
  red[tid][0] = m0*fcw[tid*2+0] + m1*fcw[(tid+256)*2+0];
  red[tid][1] = m0*fcw[tid*2+1] + m1*fcw[(tid+256)*2+1];
  __syncthreads();
  for (int st=128; st; st>>=1){
    if (tid<st){ red[tid][0]+=red[tid+st][0]; red[tid][1]+=red[tid+st][1]; }
    __syncthreads();
  }
  if (tid==0){ out[b*2+0]=red[0][0]+fcb[0]; out[b*2+1]=red[0][1]+fcb[1]; }
}

extern "C" void kernel_launch(void* const* d_in, const int* in_sizes, int n_in,
                              void* d_out, int out_size, void* d_ws, size_t ws_size,
                              hipStream_t stream)
{
  const float* x     = (const float*)d_in[0];
  const float* emb_w = (const float*)d_in[1];
  const float* emb_b = (const float*)d_in[2];
  const float* pos   = (const float*)d_in[3];
  const float* ln1_g = (const float*)d_in[4];
  const float* ln1_b = (const float*)d_in[5];
  const float* wq    = (const float*)d_in[6];
  const float* bq    = (const float*)d_in[7];
  const float* wk    = (const float*)d_in[8];
  const float* bk    = (const float*)d_in[9];
  const float* wv    = (const float*)d_in[10];
  const float* bv    = (const float*)d_in[11];
  const float* wo    = (const float*)d_in[12];
  const float* bo    = (const float*)d_in[13];
  const float* proj  = (const float*)d_in[14];
  const float* ln2_g = (const float*)d_in[15];
  const float* ln2_b = (const float*)d_in[16];
  const float* w1    = (const float*)d_in[17];
  const float* b1    = (const float*)d_in[18];
  const float* w2    = (const float*)d_in[19];
  const float* b2    = (const float*)d_in[20];
  const float* fc_w  = (const float*)d_in[21];
  const float* fc_b  = (const float*)d_in[22];
  float* out = (float*)d_out;

  const size_t W55 = (size_t)512*512, W52 = (size_t)512*2048;
  const size_t WCAT = (size_t)2560*512;

  char* p = (char*)d_ws;
  auto take = [&](size_t bytes)->char*{
    char* r = p; p += (bytes + 255) & ~(size_t)255; return r;
  };
  bf16* Wcat = (bf16*)take(L_*WCAT*2);
  bf16* woT  = (bf16*)take(L_*W55*2);
  bf16* w1T  = (bf16*)take(L_*W52*2);
  bf16* w2T  = (bf16*)take(L_*W52*2);
  bf16* embT = (bf16*)take((size_t)64*512*2);
  bf16* xbf  = (bf16*)take((size_t)B_*S_*DIN_*2);
  float* bcat= (float*)take(L_*2560*4);
  const size_t fixed_bytes = (size_t)(p - (char*)d_ws);

  int NB = 64; size_t need = 0;
  for (;; NB >>= 1){
    size_t RC = (size_t)NB*S_, nbh = (size_t)NB*H_;
    need = fixed_bytes + RC*7168 + nbh*(16384+256+4) + 65536;
    if (need <= ws_size || NB == 1) break;
  }
  if (need > ws_size) return;
  const size_t RC = (size_t)NB*S_;
  const int NBH = NB*H_, rows = (int)RC;

  float* hbuf = (float*)take(RC*512*4);
  bf16*  qpb  = (bf16*)take(RC*512*2);    // qp bf16 ┐ contiguous = ffn hidden
  float* ddk  = (float*)take(RC*512*4);   // ddk'    │ (bf16 RC x 2048)
  bf16*  vbf  = (bf16*)take(RC*512*2);    // v bf16  ┘
  bf16*  ybf  = (bf16*)take(RC*512*2);
  float* ctx  = (float*)take((size_t)NBH*4096*4);
  float* kps  = (float*)take((size_t)NBH*64*4);
  unsigned* kmaxU = (unsigned*)take((size_t)NBH*4);
  bf16* hidbf = (bf16*)qpb;               // spans qpb+ddk+vbf = RC*4096 B

  dim3 blk(256);

  // ---- per-launch weight prep ----
  for (int l=0; l<L_; ++l){
    bf16* Wl = Wcat + (size_t)l*WCAT;
    float* bl = bcat + (size_t)l*2560;
    convT_k<<<dim3(16,16), blk, 0, stream>>>(wq + l*W55, Wl, 512, 512, 0,    128);
    projw_k<<<dim3(8,8),   blk, 0, stream>>>(wq + l*W55, proj + l*4096, Wl, 64);
    convT_k<<<dim3(16,16), blk, 0, stream>>>(wk + l*W55, Wl, 512, 512, 1024, 128);
    projw_k<<<dim3(8,8),   blk, 0, stream>>>(wk + l*W55, proj + l*4096, Wl, 1024+64);
    convT_k<<<dim3(16,16), blk, 0, stream>>>(wv + l*W55, Wl, 512, 512, 2048, 64);
    bpack_k<<<10, blk, 0, stream>>>(bq + l*512, bk + l*512, bv + l*512, proj + l*4096, bl);
    convT_k<<<dim3(16,16), blk, 0, stream>>>(wo + l*W55, woT + l*W55, 512, 512, 0, 64);
    convT_k<<<dim3(64,16), blk, 0, stream>>>(w1 + l*W52, w1T + l*W52, 512, 2048, 0, 64);
    convT_k<<<dim3(16,64), blk, 0, stream>>>(w2 + l*W52, w2T + l*W52, 2048, 512, 0, 64);
  }
  convT_k<<<dim3(16,2), blk, 0, stream>>>(emb_w, embT, 64, 512, 0, 64);
  conv_k<<<(B_*S_*DIN_/4 + 255)/256, blk, 0, stream>>>(x, xbf, B_*S_*DIN_/4);

  const int rg = (rows + 127)/128;

  for (int bc = 0; bc < B_/NB; ++bc){
    const bf16* xc = xbf + (size_t)bc*RC*DIN_;
    float* outc = out + (size_t)bc*NB*2;

    gemm2_k<0,1,0><<<4*rg, blk, 0, stream>>>(
        xc, embT, emb_b, pos, hbuf, nullptr, rows, 512, 64, S_, 4);

    for (int l=0; l<L_; ++l){
      ln_k<<<2048, blk, 0, stream>>>(hbuf, ln1_g + l*512, ln1_b + l*512, ybf, rows);
      kinit_k<<<(NBH+255)/256, blk, 0, stream>>>(kmaxU, NBH);
      gemm_mega_k<<<20*rg, blk, 0, stream>>>(
          ybf, Wcat + (size_t)l*WCAT, bcat + (size_t)l*2560, rows,
          qpb, ddk, vbf, kmaxU, 20);
      fctx_k<<<NBH, blk, 0, stream>>>(ddk, vbf, kmaxU, ctx, kps);
      attnout_k<<<dim3(NBH, (S_+63)/64), blk, 0, stream>>>(qpb, ctx, kps, ybf);
      gemm2_k<0,1,0><<<4*rg, blk, 0, stream>>>(
          ybf, woT + l*W55, bo + l*512, hbuf, hbuf, nullptr, rows, 512, 512, 0, 4);
      ln_k<<<2048, blk, 0, stream>>>(hbuf, ln2_g + l*512, ln2_b + l*512, ybf, rows);
      gemm2_k<1,0,1><<<16*rg, blk, 0, stream>>>(
          ybf, w1T + l*W52, b1 + l*2048, nullptr, nullptr, hidbf, rows, 2048, 512, 0, 16);
      gemm2_k<0,1,0><<<4*rg, blk, 0, stream>>>(
          hidbf, w2T + l*W52, b2 + l*512, hbuf, hbuf, nullptr, rows, 512, 2048, 0, 4);
    }
    head_k<<<NB, blk, 0, stream>>>(hbuf, fc_w, fc_b, outc);
  }
}

// Round 8
// 3915.451 us; speedup vs baseline: 1.2452x; 1.0472x over previous
//
#include <hip/hip_runtime.h>
#include <hip/hip_bf16.h>

#define B_   64
#define S_   800
#define DIN_ 64
#define D_   512
#define H_   8
#define DH_  64
#define M_   64
#define L_   2
#define FF_  2048

typedef __hip_bfloat16 bf16;
typedef __attribute__((ext_vector_type(8))) short bf16x8;
typedef __attribute__((ext_vector_type(4))) float f32x4;

#define NORM_ 0.35355339059327373f   // 64^(-1/4)

__device__ __forceinline__ unsigned flipf(float f){
  unsigned u = __float_as_uint(f);
  return u ^ (((unsigned)((int)u >> 31)) | 0x80000000u);
}
__device__ __forceinline__ float unflipf(unsigned u){
  unsigned b = (u & 0x80000000u) ? (u ^ 0x80000000u) : ~u;
  return __uint_as_float(b);
}
__device__ __forceinline__ float gelu_f(float x){
  float x3 = x*x*x;
  return 0.5f*x*(1.f + tanhf(0.7978845608028654f*(x + 0.044715f*x3)));
}
__device__ __forceinline__ void st_bf4(bf16* p, float4 v){
  union { bf16 b[4]; unsigned long long u; } q;
  q.b[0]=__float2bfloat16(v.x); q.b[1]=__float2bfloat16(v.y);
  q.b[2]=__float2bfloat16(v.z); q.b[3]=__float2bfloat16(v.w);
  *(unsigned long long*)p = q.u;
}
__device__ __forceinline__ void gld16(const void* g, void* l){
  __builtin_amdgcn_global_load_lds((const __attribute__((address_space(1))) void*)g,
                                   (__attribute__((address_space(3))) void*)l, 16, 0, 0);
}

// XCD-chunked bijective block swizzle (m204)
__device__ __forceinline__ void swz_xy(int gx, int& bx, int& by){
  const int nwg = (int)gridDim.x, orig = (int)blockIdx.x;
  const int q = nwg>>3, r = nwg&7;
  const int xcd = orig&7, lin = orig>>3;
  const int wg = (xcd<r ? xcd*(q+1) : r*(q+1)+(xcd-r)*q) + lin;
  bx = wg % gx;  by = wg / gx;
}

// ================= 256x256 / BK=64 tile core (512 thr, 8 waves 2x4) ========
// A bf16 [rows][K], Wt bf16 [N][K].  2-buffer LDS (128 KB), per K-tile:
// stage next (8 x gld16) -> 24 x ds_read_b128 -> 128 MFMA -> __syncthreads.
// Per-iter MFMA work (~2500 cyc) >> load latency -> drain stall is hidden.
// LDS swizzle: 16B chunk q of row r holds global chunk q ^ ((r>>1)&7);
// write side pre-swizzles the GLOBAL source (gld16 dest stays linear),
// read side applies the same XOR -> each frag read spreads 16 rows over
// all 8 bank-quads (2 lanes/bank = free, m136).
__device__ __forceinline__ void gemm_tile256(const bf16* __restrict__ A,
                                             const bf16* __restrict__ Wt,
                                             int rows, int K, int bx, int by,
                                             f32x4 (&acc)[8][4])
{
  __shared__ bf16 As[2][16384];
  __shared__ bf16 Bs[2][16384];
  const int tid = threadIdx.x, wave = tid>>6, lane = tid&63;
  const int wr = wave>>2, wc = wave&3;
  const int lr = lane&15, hi = lane>>4;
  const int row0 = by*256, col0 = bx*256;
  const int srow = tid>>3;                       // 0..63
  const int scol = ((tid&7) ^ ((srow>>1)&7))*8;  // pre-swizzled source chunk
  const int keyq = (lr>>1)&7;                    // read-side XOR key
  const bf16* gA[4]; const bf16* gB[4];
  #pragma unroll
  for (int i=0;i<4;i++){
    const int ra = min(row0 + i*64 + srow, rows-1);
    gA[i] = A  + (size_t)ra*K + scol;
    gB[i] = Wt + (size_t)(col0 + i*64 + srow)*K + scol;
  }
  const int dbase = wave*512;                    // element offset of wave slot
  const int NT = K>>6;
  #pragma unroll
  for (int i=0;i<4;i++){
    gld16(gA[i], &As[0][i*4096 + dbase]);
    gld16(gB[i], &Bs[0][i*4096 + dbase]);
  }
  __syncthreads();
  for (int t=0; t<NT; ++t){
    const int p = t&1;
    if (t+1 < NT){
      const int k0 = (t+1)<<6;
      #pragma unroll
      for (int i=0;i<4;i++){
        gld16(gA[i] + k0, &As[p^1][i*4096 + dbase]);
        gld16(gB[i] + k0, &Bs[p^1][i*4096 + dbase]);
      }
    }
    #pragma unroll
    for (int ks=0; ks<2; ++ks){
      const int co = ((ks*4 + hi) ^ keyq)*8;
      bf16x8 af[8], bv[4];
      #pragma unroll
      for (int mi=0;mi<8;mi++)
        af[mi] = *(const bf16x8*)&As[p][(wr*128 + mi*16 + lr)*64 + co];
      #pragma unroll
      for (int ni=0;ni<4;ni++)
        bv[ni] = *(const bf16x8*)&Bs[p][(wc*64 + ni*16 + lr)*64 + co];
      #pragma unroll
      for (int mi=0;mi<8;mi++)
        #pragma unroll
        for (int ni=0;ni<4;ni++)
          acc[mi][ni] = __builtin_amdgcn_mfma_f32_16x16x32_bf16(af[mi], bv[ni], acc[mi][ni], 0,0,0);
    }
    __syncthreads();   // drains stage (vmcnt) + lgkm; swaps buffers safely
  }
}

// ---------------- standard 256-tile GEMM -----------------------------------
template<int ACT, int RES, int OUTB>
__global__ __launch_bounds__(512,2)
void gemm256_k(const bf16* __restrict__ A, const bf16* __restrict__ Wt,
               const float* __restrict__ bias, const float* __restrict__ res,
               float* __restrict__ Cf, bf16* __restrict__ Cb,
               int rows, int N, int K, int gx)
{
  int bx, by;  swz_xy(gx, bx, by);
  f32x4 acc[8][4];
  #pragma unroll
  for (int i=0;i<8;i++)
    #pragma unroll
    for (int j=0;j<4;j++) acc[i][j] = (f32x4){0.f,0.f,0.f,0.f};
  gemm_tile256(A, Wt, rows, K, bx, by, acc);
  const int tid=threadIdx.x, wave=tid>>6, lane=tid&63;
  const int wr=wave>>2, wc=wave&3, lr=lane&15, hi=lane>>4;
  const int row0=by*256, col0=bx*256;
  #pragma unroll
  for (int mi=0;mi<8;mi++){
    #pragma unroll
    for (int i=0;i<4;i++){
      const int r = row0 + wr*128 + mi*16 + hi*4 + i;
      if (r >= rows) continue;
      #pragma unroll
      for (int ni=0;ni<4;ni++){
        const int c = col0 + wc*64 + ni*16 + lr;
        float v = acc[mi][ni][i] + bias[c];
        if (ACT) v = gelu_f(v);
        if (RES) v += res[(size_t)r*N + c];
        if (OUTB) Cb[(size_t)r*N + c] = __float2bfloat16(v);
        else      Cf[(size_t)r*N + c] = v;
      }
    }
  }
}

// ---------------- mega 256-tile GEMM: N=2560 -------------------------------
// col quarters (64 each): gq = bx*4+wc.  bx<4: q/ddq pairs, bx in [4,8): k/ddk,
// bx in {8,9}: v.  Even wc = raw (diag), odd wc = dd.
__global__ __launch_bounds__(512,2)
void mega256_k(const bf16* __restrict__ A, const bf16* __restrict__ Wcat,
               const float* __restrict__ bcat, int rows,
               bf16* __restrict__ qpb, float* __restrict__ ddk,
               bf16* __restrict__ vbf, unsigned* __restrict__ kmaxU, int gx)
{
  __shared__ float diagL[2][256];
  int bx, by;  swz_xy(gx, bx, by);
  f32x4 acc[8][4];
  #pragma unroll
  for (int i=0;i<8;i++)
    #pragma unroll
    for (int j=0;j<4;j++) acc[i][j] = (f32x4){0.f,0.f,0.f,0.f};
  gemm_tile256(A, Wcat, rows, 512, bx, by, acc);
  const int tid=threadIdx.x, wave=tid>>6, lane=tid&63;
  const int wr=wave>>2, wc=wave&3, lr=lane&15, hi=lane>>4;
  const int row0 = by*256;
  const int cbase = bx*256 + wc*64;
  if (bx < 8 && !(wc&1)){     // raw q/k wave: diag = 0.5*(1/8)*sum((v+b)^2)
    #pragma unroll
    for (int mi=0;mi<8;mi++){
      #pragma unroll
      for (int i=0;i<4;i++){
        float s = 0.f;
        #pragma unroll
        for (int ni=0;ni<4;ni++){
          float v = acc[mi][ni][i] + bcat[cbase + ni*16 + lr];
          s += v*v;
        }
        s += __shfl_xor(s,1); s += __shfl_xor(s,2);
        s += __shfl_xor(s,4); s += __shfl_xor(s,8);
        if (lr==0) diagL[wc>>1][wr*128 + mi*16 + hi*4 + i] = 0.0625f*s;
      }
    }
  }
  __syncthreads();
  if (bx < 8){
    if (wc&1){                // dd wave
      const int isK = bx>>2;
      const int h = (bx&3)*2 + (wc>>1);
      #pragma unroll
      for (int mi=0;mi<8;mi++){
        #pragma unroll
        for (int i=0;i<4;i++){
          const int r = row0 + wr*128 + mi*16 + hi*4 + i;
          float vv[4]; float mx = -3.4e38f;
          #pragma unroll
          for (int ni=0;ni<4;ni++){
            vv[ni] = acc[mi][ni][i] + bcat[cbase + ni*16 + lr];
            mx = fmaxf(mx, vv[ni]);
          }
          mx = fmaxf(mx, __shfl_xor(mx,1)); mx = fmaxf(mx, __shfl_xor(mx,2));
          mx = fmaxf(mx, __shfl_xor(mx,4)); mx = fmaxf(mx, __shfl_xor(mx,8));
          if (r < rows){
            const float dg = diagL[wc>>1][wr*128 + mi*16 + hi*4 + i];
            if (!isK){
              #pragma unroll
              for (int ni=0;ni<4;ni++)
                qpb[(size_t)r*512 + h*64 + ni*16 + lr] =
                    __float2bfloat16(0.125f*(expf(vv[ni] - dg - mx) + 1e-4f));
            } else {
              if (lr==0) atomicMax(&kmaxU[(r/S_)*8 + h], flipf(mx));
              #pragma unroll
              for (int ni=0;ni<4;ni++)
                ddk[(size_t)r*512 + h*64 + ni*16 + lr] = vv[ni] - dg;
            }
          }
        }
      }
    }
  } else {                    // v block
    const int colb = (bx-8)*256 + wc*64;
    #pragma unroll
    for (int mi=0;mi<8;mi++){
      #pragma unroll
      for (int i=0;i<4;i++){
        const int r = row0 + wr*128 + mi*16 + hi*4 + i;
        if (r >= rows) continue;
        #pragma unroll
        for (int ni=0;ni<4;ni++){
          const int c = colb + ni*16 + lr;
          vbf[(size_t)r*512 + c] = __float2bfloat16(acc[mi][ni][i] + bcat[2048 + c]);
        }
      }
    }
  }
}

// ================= old 128x128 core (kept for embed, K=64) =================
__device__ __forceinline__ void gemm_tile(const bf16* __restrict__ A,
                                          const bf16* __restrict__ Wt,
                                          int rows, int K, int bx, int by,
                                          f32x4 (&acc)[4][4])
{
  __shared__ bf16 As[3*4096];
  __shared__ bf16 Bs[3*4096];
  const int tid = threadIdx.x, wave = tid>>6, lane = tid&63;
  const int row0 = by*128, col0 = bx*128;
  const int wm = (wave>>1)*64, wn = (wave&1)*64;
  const int lr = lane&15;
  const int lk = ((lane>>4) ^ ((lane>>1)&3))*8;
  const int c0 = wave*2, c1 = c0+1;
  const int sub = lane>>2;
  const int kq = (((lane&3) ^ ((lane>>3)&3)))*8;
  const int ra0 = min(row0 + c0*16 + sub, rows-1);
  const int ra1 = min(row0 + c1*16 + sub, rows-1);
  const bf16* gA0 = A + (size_t)ra0*K + kq;
  const bf16* gA1 = A + (size_t)ra1*K + kq;
  const bf16* gB0 = Wt + (size_t)(col0 + c0*16 + sub)*K + kq;
  const bf16* gB1 = Wt + (size_t)(col0 + c1*16 + sub)*K + kq;
  const int o0 = c0*512, o1 = c1*512;
  const int nt = K>>5;
  gld16(gA0, &As[o0]);  gld16(gA1, &As[o1]);
  gld16(gB0, &Bs[o0]);  gld16(gB1, &Bs[o1]);
  __syncthreads();
  int cur = 0;
  for (int t=0; t<nt; ++t){
    const int nxt = (cur+4096 > 8192) ? 0 : cur+4096;
    if (t+1 < nt){
      const int k0 = (t+1)*32;
      gld16(gA0+k0, &As[nxt+o0]);  gld16(gA1+k0, &As[nxt+o1]);
      gld16(gB0+k0, &Bs[nxt+o0]);  gld16(gB1+k0, &Bs[nxt+o1]);
    }
    bf16x8 af[4], bv[4];
    #pragma unroll
    for (int mi=0;mi<4;mi++) af[mi] = *(const bf16x8*)&As[cur + (wm+mi*16+lr)*32 + lk];
    #pragma unroll
    for (int ni=0;ni<4;ni++) bv[ni] = *(const bf16x8*)&Bs[cur + (wn+ni*16+lr)*32 + lk];
    #pragma unroll
    for (int mi=0;mi<4;mi++)
      #pragma unroll
      for (int ni=0;ni<4;ni++)
        acc[mi][ni] = __builtin_amdgcn_mfma_f32_16x16x32_bf16(af[mi], bv[ni], acc[mi][ni], 0,0,0);
    __syncthreads();
    cur = nxt;
  }
}

template<int ACT, int RES, int OUTB>
__global__ __launch_bounds__(256)
void gemm2_k(const bf16* __restrict__ A, const bf16* __restrict__ Wt,
             const float* __restrict__ bias, const float* __restrict__ res,
             float* __restrict__ Cf, bf16* __restrict__ Cb,
             int rows, int N, int K, int res_mod, int gx)
{
  int bx, by;  swz_xy(gx, bx, by);
  f32x4 acc[4][4];
  #pragma unroll
  for (int i=0;i<4;i++)
    #pragma unroll
    for (int j=0;j<4;j++) acc[i][j] = (f32x4){0.f,0.f,0.f,0.f};
  gemm_tile(A, Wt, rows, K, bx, by, acc);
  const int tid=threadIdx.x, wave=tid>>6, lane=tid&63;
  const int wm=(wave>>1)*64, wn=(wave&1)*64, lr=lane&15, hi=lane>>4;
  const int row0=by*128, col0=bx*128;
  #pragma unroll
  for (int mi=0;mi<4;mi++){
    #pragma unroll
    for (int i=0;i<4;i++){
      const int r = row0 + wm + mi*16 + hi*4 + i;
      if (r >= rows) continue;
      #pragma unroll
      for (int ni=0;ni<4;ni++){
        const int c = col0 + wn + ni*16 + lr;
        float v = acc[mi][ni][i] + bias[c];
        if (ACT) v = gelu_f(v);
        if (RES) v += res[(size_t)(res_mod ? (r % res_mod) : r)*N + c];
        if (OUTB) Cb[(size_t)r*N + c] = __float2bfloat16(v);
        else      Cf[(size_t)r*N + c] = v;
      }
    }
  }
}

// ------- weight transpose+convert with column remap ------------------------
__global__ __launch_bounds__(256)
void convT_k(const float* __restrict__ src, bf16* __restrict__ dst, int K, int N,
             int mapbase, int mapstride)
{
  __shared__ float t[32][33];
  const int n0 = blockIdx.x*32, k0 = blockIdx.y*32;
  const int j = threadIdx.x&31, i0 = threadIdx.x>>5;
  #pragma unroll
  for (int i=i0; i<32; i+=8) t[i][j] = src[(size_t)(k0+i)*N + n0 + j];
  __syncthreads();
  #pragma unroll
  for (int i=i0; i<32; i+=8){
    const int n = n0 + i;
    const int rn = mapbase + (n>>6)*mapstride + (n&63);
    dst[(size_t)rn*K + k0 + j] = __float2bfloat16(t[j][i]);
  }
}

__global__ void conv_k(const float* __restrict__ src, bf16* __restrict__ dst, int n4)
{
  int i = blockIdx.x*256 + threadIdx.x;
  if (i < n4){ float4 v = ((const float4*)src)[i]; st_bf4(dst + (size_t)i*4, v); }
}

// folded feature weight into Wcat: out row = mapbase + h*128 + m
__global__ __launch_bounds__(256)
void projw_k(const float* __restrict__ w, const float* __restrict__ proj,
             bf16* __restrict__ Wcat, int mapbase)
{
  __shared__ float pj[64][64];
  __shared__ float wsh[64][65];
  const int h = blockIdx.x, c0 = blockIdx.y*64;
  const int tid = threadIdx.x, lane = tid&63, tg = tid>>6;
  for (int i=tid; i<4096; i+=256) pj[i>>6][i&63] = proj[i];
  for (int i=tg; i<64; i+=4) wsh[i][lane] = w[(size_t)(c0+i)*512 + h*64 + lane];
  __syncthreads();
  float acc[16];
  #pragma unroll
  for (int j=0;j<16;j++) acc[j]=0.f;
  for (int d=0; d<64; ++d){
    float wv = wsh[lane][d];
    #pragma unroll
    for (int j=0;j<16;j++) acc[j] += wv * pj[tg*16+j][d];
  }
  #pragma unroll
  for (int j=0;j<16;j++)
    Wcat[(size_t)(mapbase + h*128 + tg*16 + j)*512 + c0 + lane] = __float2bfloat16(acc[j]*NORM_);
}

// bias pack for the interleaved 2560-col layout
__global__ void bpack_k(const float* __restrict__ bq, const float* __restrict__ bk,
                        const float* __restrict__ bv, const float* __restrict__ proj,
                        float* __restrict__ bl)
{
  int idx = blockIdx.x*256 + threadIdx.x;
  if (idx >= 2560) return;
  float v;
  if (idx < 2048){
    const float* bsrc = (idx<1024)? bq : bk;
    int t = idx & 1023;
    int h = t>>7, w = t&127;
    if (w < 64) v = bsrc[h*64+w];
    else {
      int m = w-64; float acc=0.f;
      for (int d=0; d<64; ++d) acc += bsrc[h*64+d]*proj[m*64+d];
      v = acc*NORM_;
    }
  } else v = bv[idx-2048];
  bl[idx] = v;
}

// ---------------- LayerNorm (grid-stride, bf16 out) ------------------------
__global__ __launch_bounds__(256)
void ln_k(const float* __restrict__ x, const float* __restrict__ g,
          const float* __restrict__ b, bf16* __restrict__ y, int nrows)
{
  const int wid = threadIdx.x>>6, lane = threadIdx.x&63;
  float4 g0 = *(const float4*)(g + lane*4);
  float4 g1 = *(const float4*)(g + 256 + lane*4);
  float4 b0 = *(const float4*)(b + lane*4);
  float4 b1 = *(const float4*)(b + 256 + lane*4);
  for (size_t row = (size_t)blockIdx.x*4 + wid; row < (size_t)nrows; row += (size_t)gridDim.x*4){
    const float* xr = x + row*D_;
    float4 v0 = *(const float4*)(xr + lane*4);
    float4 v1 = *(const float4*)(xr + 256 + lane*4);
    float s  = v0.x+v0.y+v0.z+v0.w + v1.x+v1.y+v1.z+v1.w;
    float ss = v0.x*v0.x+v0.y*v0.y+v0.z*v0.z+v0.w*v0.w
             + v1.x*v1.x+v1.y*v1.y+v1.z*v1.z+v1.w*v1.w;
    #pragma unroll
    for (int o=32;o;o>>=1){ s += __shfl_xor(s,o); ss += __shfl_xor(ss,o); }
    const float mean = s*(1.f/D_);
    const float rstd = rsqrtf(ss*(1.f/D_) - mean*mean + 1e-5f);
    float4 o0, o1;
    o0.x=(v0.x-mean)*rstd*g0.x+b0.x; o0.y=(v0.y-mean)*rstd*g0.y+b0.y;
    o0.z=(v0.z-mean)*rstd*g0.z+b0.z; o0.w=(v0.w-mean)*rstd*g0.w+b0.w;
    o1.x=(v1.x-mean)*rstd*g1.x+b1.x; o1.y=(v1.y-mean)*rstd*g1.y+b1.y;
    o1.z=(v1.z-mean)*rstd*g1.z+b1.z; o1.w=(v1.w-mean)*rstd*g1.w+b1.w;
    bf16* yr = y + row*D_;
    st_bf4(yr + lane*4, o0);
    st_bf4(yr + 256 + lane*4, o1);
  }
}

__global__ void kinit_k(unsigned* __restrict__ kmax, int n){
  int i = blockIdx.x*256 + threadIdx.x;
  if (i < n) kmax[i] = 0u;
}

// ------- fused featK + kps + ctx: per-(b,h) block --------------------------
__global__ __launch_bounds__(256)
void fctx_k(const float* __restrict__ ddk, const bf16* __restrict__ vbf,
            const unsigned* __restrict__ kmaxU,
            float* __restrict__ ctx, float* __restrict__ kps)
{
  __shared__ float kc[32][64], vc[32][64];
  const int bh = blockIdx.x, tid = threadIdx.x;
  const int b = bh>>3, h = bh&7;
  const float stab = unflipf(kmaxU[bh]);
  const int mq = tid>>4, dq = tid&15;
  const int cc = (tid&15)*4;
  float acc[4][4];
  #pragma unroll
  for (int i=0;i<4;i++)
    #pragma unroll
    for (int j=0;j<4;j++) acc[i][j]=0.f;
  float kpart[4] = {0.f,0.f,0.f,0.f};
  for (int s0=0; s0<S_; s0+=32){
    #pragma unroll
    for (int ii=0; ii<2; ++ii){
      const int rr = (tid>>4) + ii*16;
      const size_t grow = (size_t)(b*S_+s0+rr)*512 + h*64 + cc;
      float4 d4 = *(const float4*)(ddk + grow);
      float4 kv;
      kv.x = 0.125f*(expf(d4.x - stab)+1e-4f);
      kv.y = 0.125f*(expf(d4.y - stab)+1e-4f);
      kv.z = 0.125f*(expf(d4.z - stab)+1e-4f);
      kv.w = 0.125f*(expf(d4.w - stab)+1e-4f);
      *(float4*)&kc[rr][cc] = kv;
      kpart[0]+=kv.x; kpart[1]+=kv.y; kpart[2]+=kv.z; kpart[3]+=kv.w;
      const bf16* vp = vbf + grow;
      float4 vv;
      vv.x = __bfloat162float(vp[0]); vv.y = __bfloat162float(vp[1]);
      vv.z = __bfloat162float(vp[2]); vv.w = __bfloat162float(vp[3]);
      *(float4*)&vc[rr][cc] = vv;
    }
    __syncthreads();
    #pragma unroll 8
    for (int ssi=0; ssi<32; ++ssi){
      float a0=kc[ssi][mq*4+0],a1=kc[ssi][mq*4+1],a2=kc[ssi][mq*4+2],a3=kc[ssi][mq*4+3];
      float b0=vc[ssi][dq*4+0],b1=vc[ssi][dq*4+1],b2=vc[ssi][dq*4+2],b3=vc[ssi][dq*4+3];
      acc[0][0]+=a0*b0; acc[0][1]+=a0*b1; acc[0][2]+=a0*b2; acc[0][3]+=a0*b3;
      acc[1][0]+=a1*b0; acc[1][1]+=a1*b1; acc[1][2]+=a1*b2; acc[1][3]+=a1*b3;
      acc[2][0]+=a2*b0; acc[2][1]+=a2*b1; acc[2][2]+=a2*b2; acc[2][3]+=a2*b3;
      acc[3][0]+=a3*b0; acc[3][1]+=a3*b1; acc[3][2]+=a3*b2; acc[3][3]+=a3*b3;
    }
    __syncthreads();
  }
  #pragma unroll
  for (int i=0;i<4;i++)
    #pragma unroll
    for (int j=0;j<4;j++)
      ctx[((size_t)bh*64 + mq*4+i)*64 + dq*4+j] = acc[i][j];
  float* kcf = &kc[0][0];
  #pragma unroll
  for (int j=0;j<4;j++) kcf[tid*4+j] = kpart[j];
  __syncthreads();
  if (tid < 64){
    const int m = tid;
    float s = 0.f;
    #pragma unroll
    for (int g=0; g<16; ++g) s += kcf[(g*16 + (m>>2))*4 + (m&3)];
    kps[bh*64 + m] = s;
  }
}

// ------- attn out: qp (bf16, precomputed in mega epilogue) -----------------
__global__ __launch_bounds__(256)
void attnout_k(const bf16* __restrict__ qpb, const float* __restrict__ ctx,
               const float* __restrict__ kps, bf16* __restrict__ out)
{
  __shared__ float cl[4096];
  __shared__ float kl[64];
  __shared__ float qL[4][64];
  const int bh = blockIdx.x, tid = threadIdx.x;
  for (int i=tid;i<4096;i+=256) cl[i] = ctx[(size_t)bh*4096 + i];
  if (tid<64) kl[tid] = kps[bh*64+tid];
  const int b = bh>>3, h = bh&7;
  const int d = tid&63, sg = tid>>6;
  const int send = min((int)(blockIdx.y*64+64), S_);
  for (int s0 = blockIdx.y*64; s0 < send; s0 += 4){
    const int sr = s0 + sg;
    const size_t rrow = (size_t)(b*S_+sr);
    float qp = __bfloat162float(qpb[rrow*512 + h*64 + d]);
    __syncthreads();
    qL[sg][d] = qp;
    __syncthreads();
    float a0=0,a1=0,a2=0,a3=0, e0=0,e1=0,e2=0,e3=0;
    #pragma unroll
    for (int m=0;m<64;m+=4){
      float q0=qL[sg][m], q1=qL[sg][m+1], q2=qL[sg][m+2], q3=qL[sg][m+3];
      a0 += q0*cl[(m  )*64+d]; a1 += q1*cl[(m+1)*64+d];
      a2 += q2*cl[(m+2)*64+d]; a3 += q3*cl[(m+3)*64+d];
      e0 += q0*kl[m]; e1 += q1*kl[m+1]; e2 += q2*kl[m+2]; e3 += q3*kl[m+3];
    }
    const float den = (e0+e1)+(e2+e3);
    const float o = ((a0+a1)+(a2+a3))/den;
    out[(rrow*H_ + h)*64 + d] = __float2bfloat16(o);
  }
}

// ---------------- head ----------------------------------------------------
__global__ __launch_bounds__(256)
void head_k(const float* __restrict__ h, const float* __restrict__ fcw,
            const float* __restrict__ fcb, float* __restrict__ out)
{
  __shared__ float red[256][2];
  const int b = blockIdx.x, tid = threadIdx.x;
  const float* hb = h + (size_t)b*S_*D_;
  float s0=0.f, s1=0.f;
  for (int s=0; s<S_; ++s){
    s0 += hb[(size_t)s*D_ + tid];
    s1 += hb[(size_t)s*D_ + tid + 256];
  }
  const float m0 = s0*(1.f/S_), m1 = s1*(1.f/S_);
  red[tid][0] = m0*fcw[tid*2+0] + m1*fcw[(tid+256)*2+0];
  red[tid][1] = m0*fcw[tid*2+1] + m1*fcw[(tid+256)*2+1];
  __syncthreads();
  for (int st=128; st; st>>=1){
    if (tid<st){ red[tid][0]+=red[tid+st][0]; red[tid][1]+=red[tid+st][1]; }
    __syncthreads();
  }
  if (tid==0){ out[b*2+0]=red[0][0]+fcb[0]; out[b*2+1]=red[0][1]+fcb[1]; }
}

extern "C" void kernel_launch(void* const* d_in, const int* in_sizes, int n_in,
                              void* d_out, int out_size, void* d_ws, size_t ws_size,
                              hipStream_t stream)
{
  const float* x     = (const float*)d_in[0];
  const float* emb_w = (const float*)d_in[1];
  const float* emb_b = (const float*)d_in[2];
  const float* pos   = (const float*)d_in[3];
  const float* ln1_g = (const float*)d_in[4];
  const float* ln1_b = (const float*)d_in[5];
  const float* wq    = (const float*)d_in[6];
  const float* bq    = (const float*)d_in[7];
  const float* wk    = (const float*)d_in[8];
  const float* bk    = (const float*)d_in[9];
  const float* wv    = (const float*)d_in[10];
  const float* bv    = (const float*)d_in[11];
  const float* wo    = (const float*)d_in[12];
  const float* bo    = (const float*)d_in[13];
  const float* proj  = (const float*)d_in[14];
  const float* ln2_g = (const float*)d_in[15];
  const float* ln2_b = (const float*)d_in[16];
  const float* w1    = (const float*)d_in[17];
  const float* b1    = (const float*)d_in[18];
  const float* w2    = (const float*)d_in[19];
  const float* b2    = (const float*)d_in[20];
  const float* fc_w  = (const float*)d_in[21];
  const float* fc_b  = (const float*)d_in[22];
  float* out = (float*)d_out;

  const size_t W55 = (size_t)512*512, W52 = (size_t)512*2048;
  const size_t WCAT = (size_t)2560*512;

  char* p = (char*)d_ws;
  auto take = [&](size_t bytes)->char*{
    char* r = p; p += (bytes + 255) & ~(size_t)255; return r;
  };
  bf16* Wcat = (bf16*)take(L_*WCAT*2);
  bf16* woT  = (bf16*)take(L_*W55*2);
  bf16* w1T  = (bf16*)take(L_*W52*2);
  bf16* w2T  = (bf16*)take(L_*W52*2);
  bf16* embT = (bf16*)take((size_t)64*512*2);
  bf16* xbf  = (bf16*)take((size_t)B_*S_*DIN_*2);
  float* bcat= (float*)take(L_*2560*4);
  const size_t fixed_bytes = (size_t)(p - (char*)d_ws);

  int NB = 64; size_t need = 0;
  for (;; NB >>= 1){
    size_t RC = (size_t)NB*S_, nbh = (size_t)NB*H_;
    need = fixed_bytes + RC*7168 + nbh*(16384+256+4) + 65536;
    if (need <= ws_size || NB == 1) break;
  }
  if (need > ws_size) return;
  const size_t RC = (size_t)NB*S_;
  const int NBH = NB*H_, rows = (int)RC;

  float* hbuf = (float*)take(RC*512*4);
  bf16*  qpb  = (bf16*)take(RC*512*2);    // qp bf16 | contiguous = ffn hidden
  float* ddk  = (float*)take(RC*512*4);   // ddk'
  bf16*  vbf  = (bf16*)take(RC*512*2);    // v bf16
  bf16*  ybf  = (bf16*)take(RC*512*2);
  float* ctx  = (float*)take((size_t)NBH*4096*4);
  float* kps  = (float*)take((size_t)NBH*64*4);
  unsigned* kmaxU = (unsigned*)take((size_t)NBH*4);
  bf16* hidbf = (bf16*)qpb;               // spans qpb+ddk+vbf = RC*4096 B

  dim3 blk(256), blk5(512);

  // ---- per-launch weight prep ----
  for (int l=0; l<L_; ++l){
    bf16* Wl = Wcat + (size_t)l*WCAT;
    float* bl = bcat + (size_t)l*2560;
    convT_k<<<dim3(16,16), blk, 0, stream>>>(wq + l*W55, Wl, 512, 512, 0,    128);
    projw_k<<<dim3(8,8),   blk, 0, stream>>>(wq + l*W55, proj + l*4096, Wl, 64);
    convT_k<<<dim3(16,16), blk, 0, stream>>>(wk + l*W55, Wl, 512, 512, 1024, 128);
    projw_k<<<dim3(8,8),   blk, 0, stream>>>(wk + l*W55, proj + l*4096, Wl, 1024+64);
    convT_k<<<dim3(16,16), blk, 0, stream>>>(wv + l*W55, Wl, 512, 512, 2048, 64);
    bpack_k<<<10, blk, 0, stream>>>(bq + l*512, bk + l*512, bv + l*512, proj + l*4096, bl);
    convT_k<<<dim3(16,16), blk, 0, stream>>>(wo + l*W55, woT + l*W55, 512, 512, 0, 64);
    convT_k<<<dim3(64,16), blk, 0, stream>>>(w1 + l*W52, w1T + l*W52, 512, 2048, 0, 64);
    convT_k<<<dim3(16,64), blk, 0, stream>>>(w2 + l*W52, w2T + l*W52, 2048, 512, 0, 64);
  }
  convT_k<<<dim3(16,2), blk, 0, stream>>>(emb_w, embT, 64, 512, 0, 64);
  conv_k<<<(B_*S_*DIN_/4 + 255)/256, blk, 0, stream>>>(x, xbf, B_*S_*DIN_/4);

  const int rg128 = (rows + 127)/128;
  const int rg256 = (rows + 255)/256;

  for (int bc = 0; bc < B_/NB; ++bc){
    const bf16* xc = xbf + (size_t)bc*RC*DIN_;
    float* outc = out + (size_t)bc*NB*2;

    gemm2_k<0,1,0><<<4*rg128, blk, 0, stream>>>(
        xc, embT, emb_b, pos, hbuf, nullptr, rows, 512, 64, S_, 4);

    for (int l=0; l<L_; ++l){
      ln_k<<<2048, blk, 0, stream>>>(hbuf, ln1_g + l*512, ln1_b + l*512, ybf, rows);
      kinit_k<<<(NBH+255)/256, blk, 0, stream>>>(kmaxU, NBH);
      mega256_k<<<10*rg256, blk5, 0, stream>>>(
          ybf, Wcat + (size_t)l*WCAT, bcat + (size_t)l*2560, rows,
          qpb, ddk, vbf, kmaxU, 10);
      fctx_k<<<NBH, blk, 0, stream>>>(ddk, vbf, kmaxU, ctx, kps);
      attnout_k<<<dim3(NBH, (S_+63)/64), blk, 0, stream>>>(qpb, ctx, kps, ybf);
      gemm256_k<0,1,0><<<2*rg256, blk5, 0, stream>>>(
          ybf, woT + l*W55, bo + l*512, hbuf, hbuf, nullptr, rows, 512, 512, 2);
      ln_k<<<2048, blk, 0, stream>>>(hbuf, ln2_g + l*512, ln2_b + l*512, ybf, rows);
      gemm256_k<1,0,1><<<8*rg256, blk5, 0, stream>>>(
          ybf, w1T + l*W52, b1 + l*2048, nullptr, nullptr, hidbf, rows, 2048, 512, 8);
      gemm256_k<0,1,0><<<2*rg256, blk5, 0, stream>>>(
          hidbf, w2T + l*W52, b2 + l*512, hbuf, hbuf, nullptr, rows, 512, 2048, 2);
    }
    head_k<<<NB, blk, 0, stream>>>(hbuf, fc_w, fc_b, outc);
  }
}

// Round 9
// 3660.267 us; speedup vs baseline: 1.3320x; 1.0697x over previous
//
#include <hip/hip_runtime.h>
#include <hip/hip_bf16.h>

#define B_   64
#define S_   800
#define DIN_ 64
#define D_   512
#define H_   8
#define DH_  64
#define M_   64
#define L_   2
#define FF_  2048

typedef __hip_bfloat16 bf16;
typedef __attribute__((ext_vector_type(8))) short bf16x8;
typedef __attribute__((ext_vector_type(4))) float f32x4;
typedef __attribute__((ext_vector_type(2))) float f32x2;

#define NORM_ 0.35355339059327373f   // 64^(-1/4)

__device__ __forceinline__ unsigned flipf(float f){
  unsigned u = __float_as_uint(f);
  return u ^ (((unsigned)((int)u >> 31)) | 0x80000000u);
}
__device__ __forceinline__ float unflipf(unsigned u){
  unsigned b = (u & 0x80000000u) ? (u ^ 0x80000000u) : ~u;
  return __uint_as_float(b);
}
__device__ __forceinline__ float bf2f(unsigned short s){
  return __uint_as_float(((unsigned)s)<<16);
}
__device__ __forceinline__ float gelu_f(float x){
  float x3 = x*x*x;
  return 0.5f*x*(1.f + tanhf(0.7978845608028654f*(x + 0.044715f*x3)));
}
__device__ __forceinline__ void st_bf4(bf16* p, float4 v){
  union { bf16 b[4]; unsigned long long u; } q;
  q.b[0]=__float2bfloat16(v.x); q.b[1]=__float2bfloat16(v.y);
  q.b[2]=__float2bfloat16(v.z); q.b[3]=__float2bfloat16(v.w);
  *(unsigned long long*)p = q.u;
}
__device__ __forceinline__ void gld16(const void* g, void* l){
  __builtin_amdgcn_global_load_lds((const __attribute__((address_space(1))) void*)g,
                                   (__attribute__((address_space(3))) void*)l, 16, 0, 0);
}

// XCD-chunked bijective block swizzle (m204)
__device__ __forceinline__ void swz_xy(int gx, int& bx, int& by){
  const int nwg = (int)gridDim.x, orig = (int)blockIdx.x;
  const int q = nwg>>3, r = nwg&7;
  const int xcd = orig&7, lin = orig>>3;
  const int wg = (xcd<r ? xcd*(q+1) : r*(q+1)+(xcd-r)*q) + lin;
  bx = wg % gx;  by = wg / gx;
}

// ================= 256x256 / BK=64 tile core (512 thr, 8 waves 2x4) ========
__device__ __forceinline__ void gemm_tile256(const bf16* __restrict__ A,
                                             const bf16* __restrict__ Wt,
                                             int rows, int K, int bx, int by,
                                             f32x4 (&acc)[8][4])
{
  __shared__ bf16 As[2][16384];
  __shared__ bf16 Bs[2][16384];
  const int tid = threadIdx.x, wave = tid>>6, lane = tid&63;
  const int wr = wave>>2, wc = wave&3;
  const int lr = lane&15, hi = lane>>4;
  const int row0 = by*256, col0 = bx*256;
  const int srow = tid>>3;
  const int scol = ((tid&7) ^ ((srow>>1)&7))*8;  // pre-swizzled source chunk
  const int keyq = (lr>>1)&7;                    // read-side XOR key
  const bf16* gA[4]; const bf16* gB[4];
  #pragma unroll
  for (int i=0;i<4;i++){
    const int ra = min(row0 + i*64 + srow, rows-1);
    gA[i] = A  + (size_t)ra*K + scol;
    gB[i] = Wt + (size_t)(col0 + i*64 + srow)*K + scol;
  }
  const int dbase = wave*512;
  const int NT = K>>6;
  #pragma unroll
  for (int i=0;i<4;i++){
    gld16(gA[i], &As[0][i*4096 + dbase]);
    gld16(gB[i], &Bs[0][i*4096 + dbase]);
  }
  __syncthreads();
  for (int t=0; t<NT; ++t){
    const int p = t&1;
    if (t+1 < NT){
      const int k0 = (t+1)<<6;
      #pragma unroll
      for (int i=0;i<4;i++){
        gld16(gA[i] + k0, &As[p^1][i*4096 + dbase]);
        gld16(gB[i] + k0, &Bs[p^1][i*4096 + dbase]);
      }
    }
    #pragma unroll
    for (int ks=0; ks<2; ++ks){
      const int co = ((ks*4 + hi) ^ keyq)*8;
      bf16x8 af[8], bv[4];
      #pragma unroll
      for (int mi=0;mi<8;mi++)
        af[mi] = *(const bf16x8*)&As[p][(wr*128 + mi*16 + lr)*64 + co];
      #pragma unroll
      for (int ni=0;ni<4;ni++)
        bv[ni] = *(const bf16x8*)&Bs[p][(wc*64 + ni*16 + lr)*64 + co];
      #pragma unroll
      for (int mi=0;mi<8;mi++)
        #pragma unroll
        for (int ni=0;ni<4;ni++)
          acc[mi][ni] = __builtin_amdgcn_mfma_f32_16x16x32_bf16(af[mi], bv[ni], acc[mi][ni], 0,0,0);
    }
    __syncthreads();
  }
}

// ---------------- standard 256-tile GEMM (res/out bf16) --------------------
template<int ACT, int RES, int OUTB>
__global__ __launch_bounds__(512,2)
void gemm256_k(const bf16* __restrict__ A, const bf16* __restrict__ Wt,
               const float* __restrict__ bias, const bf16* __restrict__ res,
               float* __restrict__ Cf, bf16* __restrict__ Cb,
               int rows, int N, int K, int gx)
{
  int bx, by;  swz_xy(gx, bx, by);
  f32x4 acc[8][4];
  #pragma unroll
  for (int i=0;i<8;i++)
    #pragma unroll
    for (int j=0;j<4;j++) acc[i][j] = (f32x4){0.f,0.f,0.f,0.f};
  gemm_tile256(A, Wt, rows, K, bx, by, acc);
  const int tid=threadIdx.x, wave=tid>>6, lane=tid&63;
  const int wr=wave>>2, wc=wave&3, lr=lane&15, hi=lane>>4;
  const int row0=by*256, col0=bx*256;
  #pragma unroll
  for (int mi=0;mi<8;mi++){
    #pragma unroll
    for (int i=0;i<4;i++){
      const int r = row0 + wr*128 + mi*16 + hi*4 + i;
      if (r >= rows) continue;
      #pragma unroll
      for (int ni=0;ni<4;ni++){
        const int c = col0 + wc*64 + ni*16 + lr;
        float v = acc[mi][ni][i] + bias[c];
        if (ACT) v = gelu_f(v);
        if (RES) v += bf2f(*(const unsigned short*)&res[(size_t)r*N + c]);
        if (OUTB) Cb[(size_t)r*N + c] = __float2bfloat16(v);
        else      Cf[(size_t)r*N + c] = v;
      }
    }
  }
}

// ---------------- mega 256-tile GEMM: N=2560 -------------------------------
__global__ __launch_bounds__(512,2)
void mega256_k(const bf16* __restrict__ A, const bf16* __restrict__ Wcat,
               const float* __restrict__ bcat, int rows,
               bf16* __restrict__ qpb, float* __restrict__ ddk,
               bf16* __restrict__ vbf, unsigned* __restrict__ kmaxU, int gx)
{
  __shared__ float diagL[2][256];
  int bx, by;  swz_xy(gx, bx, by);
  f32x4 acc[8][4];
  #pragma unroll
  for (int i=0;i<8;i++)
    #pragma unroll
    for (int j=0;j<4;j++) acc[i][j] = (f32x4){0.f,0.f,0.f,0.f};
  gemm_tile256(A, Wcat, rows, 512, bx, by, acc);
  const int tid=threadIdx.x, wave=tid>>6, lane=tid&63;
  const int wr=wave>>2, wc=wave&3, lr=lane&15, hi=lane>>4;
  const int row0 = by*256;
  const int cbase = bx*256 + wc*64;
  if (bx < 8 && !(wc&1)){
    #pragma unroll
    for (int mi=0;mi<8;mi++){
      #pragma unroll
      for (int i=0;i<4;i++){
        float s = 0.f;
        #pragma unroll
        for (int ni=0;ni<4;ni++){
          float v = acc[mi][ni][i] + bcat[cbase + ni*16 + lr];
          s += v*v;
        }
        s += __shfl_xor(s,1); s += __shfl_xor(s,2);
        s += __shfl_xor(s,4); s += __shfl_xor(s,8);
        if (lr==0) diagL[wc>>1][wr*128 + mi*16 + hi*4 + i] = 0.0625f*s;
      }
    }
  }
  __syncthreads();
  if (bx < 8){
    if (wc&1){
      const int isK = bx>>2;
      const int h = (bx&3)*2 + (wc>>1);
      #pragma unroll
      for (int mi=0;mi<8;mi++){
        #pragma unroll
        for (int i=0;i<4;i++){
          const int r = row0 + wr*128 + mi*16 + hi*4 + i;
          float vv[4]; float mx = -3.4e38f;
          #pragma unroll
          for (int ni=0;ni<4;ni++){
            vv[ni] = acc[mi][ni][i] + bcat[cbase + ni*16 + lr];
            mx = fmaxf(mx, vv[ni]);
          }
          mx = fmaxf(mx, __shfl_xor(mx,1)); mx = fmaxf(mx, __shfl_xor(mx,2));
          mx = fmaxf(mx, __shfl_xor(mx,4)); mx = fmaxf(mx, __shfl_xor(mx,8));
          if (r < rows){
            const float dg = diagL[wc>>1][wr*128 + mi*16 + hi*4 + i];
            if (!isK){
              #pragma unroll
              for (int ni=0;ni<4;ni++)
                qpb[(size_t)r*512 + h*64 + ni*16 + lr] =
                    __float2bfloat16(0.125f*(expf(vv[ni] - dg - mx) + 1e-4f));
            } else {
              if (lr==0) atomicMax(&kmaxU[(r/S_)*8 + h], flipf(mx));
              #pragma unroll
              for (int ni=0;ni<4;ni++)
                ddk[(size_t)r*512 + h*64 + ni*16 + lr] = vv[ni] - dg;
            }
          }
        }
      }
    }
  } else {
    const int colb = (bx-8)*256 + wc*64;
    #pragma unroll
    for (int mi=0;mi<8;mi++){
      #pragma unroll
      for (int i=0;i<4;i++){
        const int r = row0 + wr*128 + mi*16 + hi*4 + i;
        if (r >= rows) continue;
        #pragma unroll
        for (int ni=0;ni<4;ni++){
          const int c = colb + ni*16 + lr;
          vbf[(size_t)r*512 + c] = __float2bfloat16(acc[mi][ni][i] + bcat[2048 + c]);
        }
      }
    }
  }
}

// ================= old 128x128 core (embed only, K=64) =====================
__device__ __forceinline__ void gemm_tile(const bf16* __restrict__ A,
                                          const bf16* __restrict__ Wt,
                                          int rows, int K, int bx, int by,
                                          f32x4 (&acc)[4][4])
{
  __shared__ bf16 As[3*4096];
  __shared__ bf16 Bs[3*4096];
  const int tid = threadIdx.x, wave = tid>>6, lane = tid&63;
  const int row0 = by*128, col0 = bx*128;
  const int wm = (wave>>1)*64, wn = (wave&1)*64;
  const int lr = lane&15;
  const int lk = ((lane>>4) ^ ((lane>>1)&3))*8;
  const int c0 = wave*2, c1 = c0+1;
  const int sub = lane>>2;
  const int kq = (((lane&3) ^ ((lane>>3)&3)))*8;
  const int ra0 = min(row0 + c0*16 + sub, rows-1);
  const int ra1 = min(row0 + c1*16 + sub, rows-1);
  const bf16* gA0 = A + (size_t)ra0*K + kq;
  const bf16* gA1 = A + (size_t)ra1*K + kq;
  const bf16* gB0 = Wt + (size_t)(col0 + c0*16 + sub)*K + kq;
  const bf16* gB1 = Wt + (size_t)(col0 + c1*16 + sub)*K + kq;
  const int o0 = c0*512, o1 = c1*512;
  const int nt = K>>5;
  gld16(gA0, &As[o0]);  gld16(gA1, &As[o1]);
  gld16(gB0, &Bs[o0]);  gld16(gB1, &Bs[o1]);
  __syncthreads();
  int cur = 0;
  for (int t=0; t<nt; ++t){
    const int nxt = (cur+4096 > 8192) ? 0 : cur+4096;
    if (t+1 < nt){
      const int k0 = (t+1)*32;
      gld16(gA0+k0, &As[nxt+o0]);  gld16(gA1+k0, &As[nxt+o1]);
      gld16(gB0+k0, &Bs[nxt+o0]);  gld16(gB1+k0, &Bs[nxt+o1]);
    }
    bf16x8 af[4], bv[4];
    #pragma unroll
    for (int mi=0;mi<4;mi++) af[mi] = *(const bf16x8*)&As[cur + (wm+mi*16+lr)*32 + lk];
    #pragma unroll
    for (int ni=0;ni<4;ni++) bv[ni] = *(const bf16x8*)&Bs[cur + (wn+ni*16+lr)*32 + lk];
    #pragma unroll
    for (int mi=0;mi<4;mi++)
      #pragma unroll
      for (int ni=0;ni<4;ni++)
        acc[mi][ni] = __builtin_amdgcn_mfma_f32_16x16x32_bf16(af[mi], bv[ni], acc[mi][ni], 0,0,0);
    __syncthreads();
    cur = nxt;
  }
}

template<int ACT, int RES, int OUTB>
__global__ __launch_bounds__(256)
void gemm2_k(const bf16* __restrict__ A, const bf16* __restrict__ Wt,
             const float* __restrict__ bias, const bf16* __restrict__ res,
             float* __restrict__ Cf, bf16* __restrict__ Cb,
             int rows, int N, int K, int res_mod, int gx)
{
  int bx, by;  swz_xy(gx, bx, by);
  f32x4 acc[4][4];
  #pragma unroll
  for (int i=0;i<4;i++)
    #pragma unroll
    for (int j=0;j<4;j++) acc[i][j] = (f32x4){0.f,0.f,0.f,0.f};
  gemm_tile(A, Wt, rows, K, bx, by, acc);
  const int tid=threadIdx.x, wave=tid>>6, lane=tid&63;
  const int wm=(wave>>1)*64, wn=(wave&1)*64, lr=lane&15, hi=lane>>4;
  const int row0=by*128, col0=bx*128;
  #pragma unroll
  for (int mi=0;mi<4;mi++){
    #pragma unroll
    for (int i=0;i<4;i++){
      const int r = row0 + wm + mi*16 + hi*4 + i;
      if (r >= rows) continue;
      #pragma unroll
      for (int ni=0;ni<4;ni++){
        const int c = col0 + wn + ni*16 + lr;
        float v = acc[mi][ni][i] + bias[c];
        if (ACT) v = gelu_f(v);
        if (RES) v += bf2f(*(const unsigned short*)&res[(size_t)(res_mod ? (r % res_mod) : r)*N + c]);
        if (OUTB) Cb[(size_t)r*N + c] = __float2bfloat16(v);
        else      Cf[(size_t)r*N + c] = v;
      }
    }
  }
}

// ------- weight transpose+convert with column remap ------------------------
__global__ __launch_bounds__(256)
void convT_k(const float* __restrict__ src, bf16* __restrict__ dst, int K, int N,
             int mapbase, int mapstride)
{
  __shared__ float t[32][33];
  const int n0 = blockIdx.x*32, k0 = blockIdx.y*32;
  const int j = threadIdx.x&31, i0 = threadIdx.x>>5;
  #pragma unroll
  for (int i=i0; i<32; i+=8) t[i][j] = src[(size_t)(k0+i)*N + n0 + j];
  __syncthreads();
  #pragma unroll
  for (int i=i0; i<32; i+=8){
    const int n = n0 + i;
    const int rn = mapbase + (n>>6)*mapstride + (n&63);
    dst[(size_t)rn*K + k0 + j] = __float2bfloat16(t[j][i]);
  }
}

__global__ void conv_k(const float* __restrict__ src, bf16* __restrict__ dst, int n4)
{
  int i = blockIdx.x*256 + threadIdx.x;
  if (i < n4){ float4 v = ((const float4*)src)[i]; st_bf4(dst + (size_t)i*4, v); }
}

__global__ __launch_bounds__(256)
void projw_k(const float* __restrict__ w, const float* __restrict__ proj,
             bf16* __restrict__ Wcat, int mapbase)
{
  __shared__ float pj[64][64];
  __shared__ float wsh[64][65];
  const int h = blockIdx.x, c0 = blockIdx.y*64;
  const int tid = threadIdx.x, lane = tid&63, tg = tid>>6;
  for (int i=tid; i<4096; i+=256) pj[i>>6][i&63] = proj[i];
  for (int i=tg; i<64; i+=4) wsh[i][lane] = w[(size_t)(c0+i)*512 + h*64 + lane];
  __syncthreads();
  float acc[16];
  #pragma unroll
  for (int j=0;j<16;j++) acc[j]=0.f;
  for (int d=0; d<64; ++d){
    float wv = wsh[lane][d];
    #pragma unroll
    for (int j=0;j<16;j++) acc[j] += wv * pj[tg*16+j][d];
  }
  #pragma unroll
  for (int j=0;j<16;j++)
    Wcat[(size_t)(mapbase + h*128 + tg*16 + j)*512 + c0 + lane] = __float2bfloat16(acc[j]*NORM_);
}

__global__ void bpack_k(const float* __restrict__ bq, const float* __restrict__ bk,
                        const float* __restrict__ bv, const float* __restrict__ proj,
                        float* __restrict__ bl)
{
  int idx = blockIdx.x*256 + threadIdx.x;
  if (idx >= 2560) return;
  float v;
  if (idx < 2048){
    const float* bsrc = (idx<1024)? bq : bk;
    int t = idx & 1023;
    int h = t>>7, w = t&127;
    if (w < 64) v = bsrc[h*64+w];
    else {
      int m = w-64; float acc=0.f;
      for (int d=0; d<64; ++d) acc += bsrc[h*64+d]*proj[m*64+d];
      v = acc*NORM_;
    }
  } else v = bv[idx-2048];
  bl[idx] = v;
}

// ---------------- LayerNorm (bf16 in, bf16 out, grid-stride) ---------------
__global__ __launch_bounds__(256)
void ln_k(const bf16* __restrict__ x, const float* __restrict__ g,
          const float* __restrict__ b, bf16* __restrict__ y, int nrows)
{
  const int wid = threadIdx.x>>6, lane = threadIdx.x&63;
  float gv[8], bv[8];
  {
    float4 t0 = *(const float4*)(g + lane*8);
    float4 t1 = *(const float4*)(g + lane*8 + 4);
    gv[0]=t0.x;gv[1]=t0.y;gv[2]=t0.z;gv[3]=t0.w;gv[4]=t1.x;gv[5]=t1.y;gv[6]=t1.z;gv[7]=t1.w;
    float4 u0 = *(const float4*)(b + lane*8);
    float4 u1 = *(const float4*)(b + lane*8 + 4);
    bv[0]=u0.x;bv[1]=u0.y;bv[2]=u0.z;bv[3]=u0.w;bv[4]=u1.x;bv[5]=u1.y;bv[6]=u1.z;bv[7]=u1.w;
  }
  for (size_t row = (size_t)blockIdx.x*4 + wid; row < (size_t)nrows; row += (size_t)gridDim.x*4){
    bf16x8 xv = *(const bf16x8*)(x + row*D_ + lane*8);
    float f[8];
    #pragma unroll
    for (int j=0;j<8;j++) f[j] = bf2f((unsigned short)xv[j]);
    float s=0.f, ss=0.f;
    #pragma unroll
    for (int j=0;j<8;j++){ s += f[j]; ss += f[j]*f[j]; }
    #pragma unroll
    for (int o=32;o;o>>=1){ s += __shfl_xor(s,o); ss += __shfl_xor(ss,o); }
    const float mean = s*(1.f/D_);
    const float rstd = rsqrtf(ss*(1.f/D_) - mean*mean + 1e-5f);
    union { bf16 bb[8]; bf16x8 v8; } o8;
    #pragma unroll
    for (int j=0;j<8;j++)
      o8.bb[j] = __float2bfloat16((f[j]-mean)*rstd*gv[j] + bv[j]);
    *(bf16x8*)(y + row*D_ + lane*8) = o8.v8;
  }
}

__global__ void kinit_k(unsigned* __restrict__ kmax, int n){
  int i = blockIdx.x*256 + threadIdx.x;
  if (i < n) kmax[i] = 0u;
}

// ------- fused featK + kps + ctx: per-(b,h) block, packed-f32 inner --------
__global__ __launch_bounds__(256)
void fctx_k(const float* __restrict__ ddk, const bf16* __restrict__ vbf,
            const unsigned* __restrict__ kmaxU,
            float* __restrict__ ctx, float* __restrict__ kps)
{
  __shared__ float kc[32][64], vc[32][64];
  const int bh = blockIdx.x, tid = threadIdx.x;
  const int b = bh>>3, h = bh&7;
  const float stab = unflipf(kmaxU[bh]);
  const int mq = tid>>4, dq = tid&15;
  const int cc = (tid&15)*4;
  f32x2 acc2[2][4];
  #pragma unroll
  for (int p=0;p<2;p++)
    #pragma unroll
    for (int j=0;j<4;j++) acc2[p][j] = (f32x2){0.f,0.f};
  float kpart[4] = {0.f,0.f,0.f,0.f};
  for (int s0=0; s0<S_; s0+=32){
    #pragma unroll
    for (int ii=0; ii<2; ++ii){
      const int rr = (tid>>4) + ii*16;
      const size_t grow = (size_t)(b*S_+s0+rr)*512 + h*64 + cc;
      float4 d4 = *(const float4*)(ddk + grow);
      float4 kv;
      kv.x = 0.125f*(expf(d4.x - stab)+1e-4f);
      kv.y = 0.125f*(expf(d4.y - stab)+1e-4f);
      kv.z = 0.125f*(expf(d4.z - stab)+1e-4f);
      kv.w = 0.125f*(expf(d4.w - stab)+1e-4f);
      *(float4*)&kc[rr][cc] = kv;
      kpart[0]+=kv.x; kpart[1]+=kv.y; kpart[2]+=kv.z; kpart[3]+=kv.w;
      const bf16* vp = vbf + grow;
      float4 vv;
      vv.x = bf2f(*(const unsigned short*)&vp[0]);
      vv.y = bf2f(*(const unsigned short*)&vp[1]);
      vv.z = bf2f(*(const unsigned short*)&vp[2]);
      vv.w = bf2f(*(const unsigned short*)&vp[3]);
      *(float4*)&vc[rr][cc] = vv;
    }
    __syncthreads();
    #pragma unroll 8
    for (int ssi=0; ssi<32; ++ssi){
      f32x2 a0 = *(const f32x2*)&kc[ssi][mq*4 + 0];
      f32x2 a1 = *(const f32x2*)&kc[ssi][mq*4 + 2];
      float4 b4 = *(const float4*)&vc[ssi][dq*4];
      acc2[0][0] += a0 * (f32x2){b4.x,b4.x};
      acc2[0][1] += a0 * (f32x2){b4.y,b4.y};
      acc2[0][2] += a0 * (f32x2){b4.z,b4.z};
      acc2[0][3] += a0 * (f32x2){b4.w,b4.w};
      acc2[1][0] += a1 * (f32x2){b4.x,b4.x};
      acc2[1][1] += a1 * (f32x2){b4.y,b4.y};
      acc2[1][2] += a1 * (f32x2){b4.z,b4.z};
      acc2[1][3] += a1 * (f32x2){b4.w,b4.w};
    }
    __syncthreads();
  }
  #pragma unroll
  for (int p=0;p<2;p++)
    #pragma unroll
    for (int j=0;j<4;j++){
      ctx[((size_t)bh*64 + mq*4 + 2*p    )*64 + dq*4+j] = acc2[p][j].x;
      ctx[((size_t)bh*64 + mq*4 + 2*p + 1)*64 + dq*4+j] = acc2[p][j].y;
    }
  float* kcf = &kc[0][0];
  #pragma unroll
  for (int j=0;j<4;j++) kcf[tid*4+j] = kpart[j];
  __syncthreads();
  if (tid < 64){
    const int m = tid;
    float s = 0.f;
    #pragma unroll
    for (int g=0; g<16; ++g) s += kcf[(g*16 + (m>>2))*4 + (m&3)];
    kps[bh*64 + m] = s;
  }
}

// ------- attn out: wave-local qL (no per-iter barriers) --------------------
__global__ __launch_bounds__(256)
void attnout_k(const bf16* __restrict__ qpb, const float* __restrict__ ctx,
               const float* __restrict__ kps, bf16* __restrict__ out)
{
  __shared__ float cl[4096];
  __shared__ float kl[64];
  __shared__ float qL[4][64];
  const int bh = blockIdx.x, tid = threadIdx.x;
  for (int i=tid;i<4096;i+=256) cl[i] = ctx[(size_t)bh*4096 + i];
  if (tid<64) kl[tid] = kps[bh*64+tid];
  __syncthreads();
  const int b = bh>>3, h = bh&7;
  const int d = tid&63, sg = tid>>6;   // sg == wave id -> qL[sg] is wave-local
  const int send = min((int)(blockIdx.y*64+64), S_);
  for (int s0 = blockIdx.y*64; s0 < send; s0 += 4){
    const int sr = s0 + sg;
    const size_t rrow = (size_t)(b*S_+sr);
    float qp = bf2f(*(const unsigned short*)&qpb[rrow*512 + h*64 + d]);
    qL[sg][d] = qp;
    float a0=0,a1=0,a2=0,a3=0, e0=0,e1=0,e2=0,e3=0;
    #pragma unroll
    for (int m=0;m<64;m+=4){
      float q0=qL[sg][m], q1=qL[sg][m+1], q2=qL[sg][m+2], q3=qL[sg][m+3];
      a0 += q0*cl[(m  )*64+d]; a1 += q1*cl[(m+1)*64+d];
      a2 += q2*cl[(m+2)*64+d]; a3 += q3*cl[(m+3)*64+d];
      e0 += q0*kl[m]; e1 += q1*kl[m+1]; e2 += q2*kl[m+2]; e3 += q3*kl[m+3];
    }
    const float den = (e0+e1)+(e2+e3);
    const float o = ((a0+a1)+(a2+a3))/den;
    out[(rrow*H_ + h)*64 + d] = __float2bfloat16(o);
  }
}

// ---------------- head (bf16 h) --------------------------------------------
__global__ __launch_bounds__(256)
void head_k(const bf16* __restrict__ h, const float* __restrict__ fcw,
            const float* __restrict__ fcb, float* __restrict__ out)
{
  __shared__ float red[256][2];
  const int b = blockIdx.x, tid = threadIdx.x;
  const bf16* hb = h + (size_t)b*S_*D_;
  float s0=0.f, s1=0.f;
  for (int s=0; s<S_; ++s){
    s0 += bf2f(*(const unsigned short*)&hb[(size_t)s*D_ + tid]);
    s1 += bf2f(*(const unsigned short*)&hb[(size_t)s*D_ + tid + 256]);
  }
  const float m0 = s0*(1.f/S_), m1 = s1*(1.f/S_);
  red[tid][0] = m0*fcw[tid*2+0] + m1*fcw[(tid+256)*2+0];
  red[tid][1] = m0*fcw[tid*2+1] + m1*fcw[(tid+256)*2+1];
  __syncthreads();
  for (int st=128; st; st>>=1){
    if (tid<st){ red[tid][0]+=red[tid+st][0]; red[tid][1]+=red[tid+st][1]; }
    __syncthreads();
  }
  if (tid==0){ out[b*2+0]=red[0][0]+fcb[0]; out[b*2+1]=red[0][1]+fcb[1]; }
}

extern "C" void kernel_launch(void* const* d_in, const int* in_sizes, int n_in,
                              void* d_out, int out_size, void* d_ws, size_t ws_size,
                              hipStream_t stream)
{
  const float* x     = (const float*)d_in[0];
  const float* emb_w = (const float*)d_in[1];
  const float* emb_b = (const float*)d_in[2];
  const float* pos   = (const float*)d_in[3];
  const float* ln1_g = (const float*)d_in[4];
  const float* ln1_b = (const float*)d_in[5];
  const float* wq    = (const float*)d_in[6];
  const float* bq    = (const float*)d_in[7];
  const float* wk    = (const float*)d_in[8];
  const float* bk    = (const float*)d_in[9];
  const float* wv    = (const float*)d_in[10];
  const float* bv    = (const float*)d_in[11];
  const float* wo    = (const float*)d_in[12];
  const float* bo    = (const float*)d_in[13];
  const float* proj  = (const float*)d_in[14];
  const float* ln2_g = (const float*)d_in[15];
  const float* ln2_b = (const float*)d_in[16];
  const float* w1    = (const float*)d_in[17];
  const float* b1    = (const float*)d_in[18];
  const float* w2    = (const float*)d_in[19];
  const float* b2    = (const float*)d_in[20];
  const float* fc_w  = (const float*)d_in[21];
  const float* fc_b  = (const float*)d_in[22];
  float* out = (float*)d_out;

  const size_t W55 = (size_t)512*512, W52 = (size_t)512*2048;
  const size_t WCAT = (size_t)2560*512;

  char* p = (char*)d_ws;
  auto take = [&](size_t bytes)->char*{
    char* r = p; p += (bytes + 255) & ~(size_t)255; return r;
  };
  bf16* Wcat = (bf16*)take(L_*WCAT*2);
  bf16* woT  = (bf16*)take(L_*W55*2);
  bf16* w1T  = (bf16*)take(L_*W52*2);
  bf16* w2T  = (bf16*)take(L_*W52*2);
  bf16* embT = (bf16*)take((size_t)64*512*2);
  bf16* xbf  = (bf16*)take((size_t)B_*S_*DIN_*2);
  bf16* posbf= (bf16*)take((size_t)S_*512*2);
  float* bcat= (float*)take(L_*2560*4);
  const size_t fixed_bytes = (size_t)(p - (char*)d_ws);

  int NB = 64; size_t need = 0;
  for (;; NB >>= 1){
    size_t RC = (size_t)NB*S_, nbh = (size_t)NB*H_;
    need = fixed_bytes + RC*6144 + nbh*(16384+256+4) + 65536;
    if (need <= ws_size || NB == 1) break;
  }
  if (need > ws_size) return;
  const size_t RC = (size_t)NB*S_;
  const int NBH = NB*H_, rows = (int)RC;

  bf16*  hbuf = (bf16*)take(RC*512*2);    // residual stream bf16
  bf16*  qpb  = (bf16*)take(RC*512*2);    // qp bf16 | contiguous = ffn hidden
  float* ddk  = (float*)take(RC*512*4);   // ddk'
  bf16*  vbf  = (bf16*)take(RC*512*2);    // v bf16
  bf16*  ybf  = (bf16*)take(RC*512*2);
  float* ctx  = (float*)take((size_t)NBH*4096*4);
  float* kps  = (float*)take((size_t)NBH*64*4);
  unsigned* kmaxU = (unsigned*)take((size_t)NBH*4);
  bf16* hidbf = (bf16*)qpb;               // spans qpb+ddk+vbf = RC*4096 B

  dim3 blk(256), blk5(512);

  // ---- per-launch weight prep ----
  for (int l=0; l<L_; ++l){
    bf16* Wl = Wcat + (size_t)l*WCAT;
    float* bl = bcat + (size_t)l*2560;
    convT_k<<<dim3(16,16), blk, 0, stream>>>(wq + l*W55, Wl, 512, 512, 0,    128);
    projw_k<<<dim3(8,8),   blk, 0, stream>>>(wq + l*W55, proj + l*4096, Wl, 64);
    convT_k<<<dim3(16,16), blk, 0, stream>>>(wk + l*W55, Wl, 512, 512, 1024, 128);
    projw_k<<<dim3(8,8),   blk, 0, stream>>>(wk + l*W55, proj + l*4096, Wl, 1024+64);
    convT_k<<<dim3(16,16), blk, 0, stream>>>(wv + l*W55, Wl, 512, 512, 2048, 64);
    bpack_k<<<10, blk, 0, stream>>>(bq + l*512, bk + l*512, bv + l*512, proj + l*4096, bl);
    convT_k<<<dim3(16,16), blk, 0, stream>>>(wo + l*W55, woT + l*W55, 512, 512, 0, 64);
    convT_k<<<dim3(64,16), blk, 0, stream>>>(w1 + l*W52, w1T + l*W52, 512, 2048, 0, 64);
    convT_k<<<dim3(16,64), blk, 0, stream>>>(w2 + l*W52, w2T + l*W52, 2048, 512, 0, 64);
  }
  convT_k<<<dim3(16,2), blk, 0, stream>>>(emb_w, embT, 64, 512, 0, 64);
  conv_k<<<(B_*S_*DIN_/4 + 255)/256, blk, 0, stream>>>(x, xbf, B_*S_*DIN_/4);
  conv_k<<<(S_*512/4 + 255)/256, blk, 0, stream>>>(pos, posbf, S_*512/4);

  const int rg128 = (rows + 127)/128;
  const int rg256 = (rows + 255)/256;

  for (int bc = 0; bc < B_/NB; ++bc){
    const bf16* xc = xbf + (size_t)bc*RC*DIN_;
    float* outc = out + (size_t)bc*NB*2;

    gemm2_k<0,1,1><<<4*rg128, blk, 0, stream>>>(
        xc, embT, emb_b, posbf, nullptr, hbuf, rows, 512, 64, S_, 4);

    for (int l=0; l<L_; ++l){
      ln_k<<<2048, blk, 0, stream>>>(hbuf, ln1_g + l*512, ln1_b + l*512, ybf, rows);
      kinit_k<<<(NBH+255)/256, blk, 0, stream>>>(kmaxU, NBH);
      mega256_k<<<10*rg256, blk5, 0, stream>>>(
          ybf, Wcat + (size_t)l*WCAT, bcat + (size_t)l*2560, rows,
          qpb, ddk, vbf, kmaxU, 10);
      fctx_k<<<NBH, blk, 0, stream>>>(ddk, vbf, kmaxU, ctx, kps);
      attnout_k<<<dim3(NBH, (S_+63)/64), blk, 0, stream>>>(qpb, ctx, kps, ybf);
      gemm256_k<0,1,1><<<2*rg256, blk5, 0, stream>>>(
          ybf, woT + l*W55, bo + l*512, hbuf, nullptr, hbuf, rows, 512, 512, 2);
      ln_k<<<2048, blk, 0, stream>>>(hbuf, ln2_g + l*512, ln2_b + l*512, ybf, rows);
      gemm256_k<1,0,1><<<8*rg256, blk5, 0, stream>>>(
          ybf, w1T + l*W52, b1 + l*2048, nullptr, nullptr, hidbf, rows, 2048, 512, 8);
      gemm256_k<0,1,1><<<2*rg256, blk5, 0, stream>>>(
          hidbf, w2T + l*W52, b2 + l*512, hbuf, nullptr, hbuf, rows, 512, 2048, 2);
    }
    head_k<<<NB, blk, 0, stream>>>(hbuf, fc_w, fc_b, outc);
  }
}